// Round 7
// baseline (288.428 us; speedup 1.0000x reference)
//
#include <hip/hip_runtime.h>
#include <hip/hip_bf16.h>

typedef __bf16 bf16_t;
typedef __bf16 bf16x4 __attribute__((ext_vector_type(4)));
typedef __bf16 bf16x8 __attribute__((ext_vector_type(8)));
typedef float  f32x4  __attribute__((ext_vector_type(4)));
typedef float  f32x8  __attribute__((ext_vector_type(8)));

#define EMBED 512
#define NH    8
#define HD    64
#define SEQ   2048
#define MTOT  8192
#define SCQ   0.18033688011112042f   // log2(e) / sqrt(64), folded into Q

__device__ __forceinline__ float gelu_f(float x) {
    return 0.5f * x * (1.0f + erff(x * 0.7071067811865475f));
}

__device__ __forceinline__ f32x4 mfma16(bf16x8 a, bf16x8 b, f32x4 c) {
    return __builtin_amdgcn_mfma_f32_16x16x32_bf16(a, b, c, 0, 0, 0);
}

union U2 { bf16x4 v; uint2 u; };
union U4 { bf16x8 v; int   x[4]; };

// ---------------------------------------------------------------------------
// Pre-convert fp32 -> bf16: x (16 segments of 256K elems) + Wq/Wk/Wv.
// ---------------------------------------------------------------------------
__global__ __launch_bounds__(256)
void convert_kernel(const float* __restrict__ x,  const float* __restrict__ Wq,
                    const float* __restrict__ Wk, const float* __restrict__ Wv,
                    bf16_t* __restrict__ xb, bf16_t* __restrict__ wb)
{
    const int y = blockIdx.y;
    const float* src; bf16_t* dst;
    if (y < 16)      { src = x + (size_t)y * 262144; dst = xb + (size_t)y * 262144; }
    else if (y == 16){ src = Wq; dst = wb; }
    else if (y == 17){ src = Wk; dst = wb + 262144; }
    else             { src = Wv; dst = wb + 524288; }
    const int base = (blockIdx.x * 256 + threadIdx.x) * 16;
    const f32x8 a = *(const f32x8*)(src + base);
    const f32x8 b = *(const f32x8*)(src + base + 8);
    *(bf16x8*)(dst + base)     = __builtin_convertvector(a, bf16x8);
    *(bf16x8*)(dst + base + 8) = __builtin_convertvector(b, bf16x8);
}

// ---------------------------------------------------------------------------
// GEMM + bias + GELU.
// MODE 0 (X,W bf16): mat 0/1 (Q,K) run OPERAND-SWAPPED (A=W,B=X) so the
//   C-layout reg-run lands on d -> bf16x4 scatter stores to [B,H,S,D];
//   mat 2 (V) keeps natural orientation -> bf16x4 runs along s to [B,H,D,S].
// MODE 1 (W fp32): natural orientation, coalesced fp32 [M,EMBED] store.
// 128 x NTILE tile, BK=64, 4 waves, register prefetch of next k-tile.
// Padded LDS stride 72 (<=2-way bank conflicts = free).
// ---------------------------------------------------------------------------
template<int MODE, int NTILE>
__global__ __launch_bounds__(256, 3)
void gemm_gelu_kernel(const bf16_t* __restrict__ Xb,
                      const bf16_t* __restrict__ Wb,   // MODE 0
                      const float*  __restrict__ Wf,   // MODE 1
                      const float*  __restrict__ Bq, const float* __restrict__ Bk,
                      const float*  __restrict__ Bv,
                      bf16_t* __restrict__ O0, bf16_t* __restrict__ O1,
                      bf16_t* __restrict__ O2, float* __restrict__ Of)
{
    constexpr int NTN = NTILE / 32;
    __shared__ __align__(16) bf16_t As[128 * 72];
    __shared__ __align__(16) bf16_t Bs[NTILE * 72];
    const int tid  = threadIdx.x;
    const int lane = tid & 63, w = tid >> 6, quad = lane >> 4, l15 = lane & 15;
    const int m0 = blockIdx.x * 128;
    int mat, n0;
    if (MODE == 0) { mat = blockIdx.y >> 2; n0 = (blockIdx.y & 3) * NTILE; }
    else           { mat = 0;               n0 = blockIdx.y * NTILE; }
    const bf16_t* W  = (MODE == 0) ? (Wb + (size_t)mat * 262144) : nullptr;
    const float*  Bi = (MODE == 1) ? Bq : (mat == 0 ? Bq : (mat == 1 ? Bk : Bv));
    const bool swp = (MODE == 0) && (mat < 2);

    const int wr = (w >> 1) * 64;
    const int wc = (w & 1) * (NTILE / 2);
    const int srow = tid >> 3, scol = (tid & 7) * 8;

    f32x4 acc[4][NTN];
#pragma unroll
    for (int a = 0; a < 4; ++a)
#pragma unroll
        for (int b = 0; b < NTN; ++b) acc[a][b] = f32x4{0.f, 0.f, 0.f, 0.f};

    bf16x8 xp[4];
    bf16x8 wpb[NTN];
    f32x8  wpf[NTN];

#pragma unroll
    for (int it = 0; it < 4; ++it)
        xp[it] = *(const bf16x8*)(Xb + (size_t)(m0 + it * 32 + srow) * EMBED + scol);
#pragma unroll
    for (int it = 0; it < NTN; ++it) {
        const int r = it * 32 + srow;
        if (MODE == 0) wpb[it] = *(const bf16x8*)(W + (size_t)(n0 + r) * EMBED + scol);
        else           wpf[it] = *(const f32x8*)(Wf + (size_t)(n0 + r) * EMBED + scol);
    }

#pragma unroll 1
    for (int kt = 0; kt < 8; ++kt) {
        __syncthreads();
#pragma unroll
        for (int it = 0; it < 4; ++it)
            *(bf16x8*)(As + (it * 32 + srow) * 72 + scol) = xp[it];
#pragma unroll
        for (int it = 0; it < NTN; ++it) {
            const int r = it * 32 + srow;
            if (MODE == 0) *(bf16x8*)(Bs + r * 72 + scol) = wpb[it];
            else *(bf16x8*)(Bs + r * 72 + scol) = __builtin_convertvector(wpf[it], bf16x8);
        }
        if (kt < 7) {
            const int k1 = (kt + 1) * 64;
#pragma unroll
            for (int it = 0; it < 4; ++it)
                xp[it] = *(const bf16x8*)(Xb + (size_t)(m0 + it * 32 + srow) * EMBED + k1 + scol);
#pragma unroll
            for (int it = 0; it < NTN; ++it) {
                const int r = it * 32 + srow;
                if (MODE == 0) wpb[it] = *(const bf16x8*)(W + (size_t)(n0 + r) * EMBED + k1 + scol);
                else           wpf[it] = *(const f32x8*)(Wf + (size_t)(n0 + r) * EMBED + k1 + scol);
            }
        }
        __syncthreads();
#pragma unroll
        for (int ks = 0; ks < 2; ++ks) {
            const int ko = (ks * 4 + quad) * 8;
            bf16x8 av[4], bv[NTN];
#pragma unroll
            for (int mt = 0; mt < 4; ++mt)
                av[mt] = *(const bf16x8*)(As + (wr + mt * 16 + l15) * 72 + ko);
#pragma unroll
            for (int nt = 0; nt < NTN; ++nt)
                bv[nt] = *(const bf16x8*)(Bs + (wc + nt * 16 + l15) * 72 + ko);
            if (swp) {
#pragma unroll
                for (int a = 0; a < NTN; ++a)
#pragma unroll
                    for (int b = 0; b < 4; ++b)
                        acc[a][b] = mfma16(bv[a], av[b], acc[a][b]);   // D: col=m, row=n
            } else {
#pragma unroll
                for (int a = 0; a < 4; ++a)
#pragma unroll
                    for (int b = 0; b < NTN; ++b)
                        acc[a][b] = mfma16(av[a], bv[b], acc[a][b]);   // D: col=n, row=m
            }
        }
    }

    if (MODE == 0 && mat < 2) {
        // acc[at][bt]: n = n0+wc+at*16+quad*4+i, m = m0+wr+bt*16+l15
        bf16_t* O = (mat == 0) ? O0 : O1;
        const float scl = (mat == 0) ? SCQ : 1.0f;
#pragma unroll
        for (int at = 0; at < 4; ++at) {
            const int nb = n0 + wc + at * 16 + quad * 4;
            const int h = nb >> 6, d0 = nb & 63;
            const f32x4 b4 = *(const f32x4*)(Bi + nb);
#pragma unroll
            for (int bt = 0; bt < 4; ++bt) {
                const int m = m0 + wr + bt * 16 + l15;
                const int bb = m >> 11, s = m & (SEQ - 1);
                bf16x4 pk;
#pragma unroll
                for (int i = 0; i < 4; ++i)
                    pk[i] = (bf16_t)(gelu_f(acc[at][bt][i] + b4[i]) * scl);
                *(bf16x4*)(O + (((size_t)(bb * NH + h)) * SEQ + s) * HD + d0) = pk;
            }
        }
    } else if (MODE == 0) {
        // V: acc[mt][nt]: m = m0+wr+mt*16+quad*4+i, n(d) = n0+wc+nt*16+l15
#pragma unroll
        for (int mt = 0; mt < 4; ++mt) {
            const int mb = m0 + wr + mt * 16 + quad * 4;
            const int bb = mb >> 11, s0 = mb & (SEQ - 1);
#pragma unroll
            for (int nt = 0; nt < 4; ++nt) {
                const int fc = n0 + wc + nt * 16 + l15;
                const int h = fc >> 6, d = fc & 63;
                const float bs = Bi[fc];
                bf16x4 pk;
#pragma unroll
                for (int i = 0; i < 4; ++i)
                    pk[i] = (bf16_t)gelu_f(acc[mt][nt][i] + bs);
                *(bf16x4*)(O2 + ((size_t)(bb * NH + h) * HD + d) * SEQ + s0) = pk;
            }
        }
    } else {
        // fp32 natural store, fully coalesced
#pragma unroll
        for (int mt = 0; mt < 4; ++mt) {
            const int mb = m0 + wr + mt * 16 + quad * 4;
#pragma unroll
            for (int nt = 0; nt < NTN; ++nt) {
                const int fc = n0 + wc + nt * 16 + l15;
                const float bs = Bi[fc];
#pragma unroll
                for (int i = 0; i < 4; ++i)
                    Of[(size_t)(mb + i) * EMBED + fc] = gelu_f(acc[mt][nt][i] + bs);
            }
        }
    }
}

// ---------------------------------------------------------------------------
// Flash attention. Q pre-scaled by log2(e)/8 => p = exp2(s), shift-free
// (global 2^c factor cancels in O/l). S^T = K*Q^T gives P[q=l15][key=quad*4+i];
// PV runs operand-swapped: A = Vt rows (b128 LDS), B = P in B-frag layout
// built IN-REGISTER via 16 dword shuffles + 8 selects (no P LDS buffer).
// O lands as [q=l15][d=quad*4+reg]; lsum is per-lane -> xor16/32 only.
// LDS = K/V double-buffer only (36.9 KB) -> 4 blocks/CU.
// ---------------------------------------------------------------------------
__global__ __launch_bounds__(256, 4)
void flash_attn_kernel(const bf16_t* __restrict__ Q,
                       const bf16_t* __restrict__ K,
                       const bf16_t* __restrict__ Vt,
                       bf16_t* __restrict__ Og)
{
    __shared__ __align__(16) bf16_t Ks[2][64 * 72];
    __shared__ __align__(16) bf16_t Vs[2][64 * 72];

    const int tid  = threadIdx.x;
    const int lane = tid & 63, w = tid >> 6, quad = lane >> 4, l15 = lane & 15;
    const int bh = blockIdx.y;
    const int q0 = blockIdx.x * 64;
    const size_t baseQK = (size_t)bh * SEQ * HD;
    const size_t baseV  = (size_t)bh * HD * SEQ;
    const int wm = w * 16;

    bf16x8 qf[2];
#pragma unroll
    for (int ks = 0; ks < 2; ++ks)
        qf[ks] = *(const bf16x8*)(Q + baseQK + (size_t)(q0 + wm + l15) * HD + ks * 32 + quad * 8);

    float lsum = 0.f;
    f32x4 oacc[4];
#pragma unroll
    for (int nt = 0; nt < 4; ++nt) oacc[nt] = f32x4{0.f, 0.f, 0.f, 0.f};

    const int r0 = tid >> 3, c0 = (tid & 7) * 8;
    bf16x8 kr0, kr1, vr0, vr1;

    kr0 = *(const bf16x8*)(K + baseQK + (size_t)r0 * HD + c0);
    kr1 = *(const bf16x8*)(K + baseQK + (size_t)(r0 + 32) * HD + c0);
    vr0 = *(const bf16x8*)(Vt + baseV + (size_t)r0 * SEQ + c0);
    vr1 = *(const bf16x8*)(Vt + baseV + (size_t)(r0 + 32) * SEQ + c0);
    *(bf16x8*)(Ks[0] + r0 * 72 + c0)        = kr0;
    *(bf16x8*)(Ks[0] + (r0 + 32) * 72 + c0) = kr1;
    *(bf16x8*)(Vs[0] + r0 * 72 + c0)        = vr0;
    *(bf16x8*)(Vs[0] + (r0 + 32) * 72 + c0) = vr1;
    kr0 = *(const bf16x8*)(K + baseQK + (size_t)(64 + r0) * HD + c0);
    kr1 = *(const bf16x8*)(K + baseQK + (size_t)(64 + r0 + 32) * HD + c0);
    vr0 = *(const bf16x8*)(Vt + baseV + (size_t)r0 * SEQ + 64 + c0);
    vr1 = *(const bf16x8*)(Vt + baseV + (size_t)(r0 + 32) * SEQ + 64 + c0);

    const int lA = (((quad * 2) & 3) << 4) | l15;       // src lane, dwords 0/1
    const int lB = (((quad * 2 + 1) & 3) << 4) | l15;   // src lane, dwords 2/3
    const bool hiq = quad >= 2;                         // pk[2c] vs pk[2c+1]

#pragma unroll 1
    for (int t = 0; t < 32; ++t) {
        __syncthreads();
        if (t + 1 < 32) {
            bf16_t* Kn = Ks[(t + 1) & 1];
            bf16_t* Vn = Vs[(t + 1) & 1];
            *(bf16x8*)(Kn + r0 * 72 + c0)        = kr0;
            *(bf16x8*)(Kn + (r0 + 32) * 72 + c0) = kr1;
            *(bf16x8*)(Vn + r0 * 72 + c0)        = vr0;
            *(bf16x8*)(Vn + (r0 + 32) * 72 + c0) = vr1;
        }
        if (t + 2 < 32) {
            const int kv = (t + 2) * 64;
            kr0 = *(const bf16x8*)(K + baseQK + (size_t)(kv + r0) * HD + c0);
            kr1 = *(const bf16x8*)(K + baseQK + (size_t)(kv + r0 + 32) * HD + c0);
            vr0 = *(const bf16x8*)(Vt + baseV + (size_t)r0 * SEQ + kv + c0);
            vr1 = *(const bf16x8*)(Vt + baseV + (size_t)(r0 + 32) * SEQ + kv + c0);
        }

        const bf16_t* Kb = Ks[t & 1];
        const bf16_t* Vb = Vs[t & 1];

        // S^T = K Q^T : lane holds S[q=l15][key = jt*16 + quad*4 + i]
        f32x4 sf[4];
#pragma unroll
        for (int jt = 0; jt < 4; ++jt) sf[jt] = f32x4{0.f, 0.f, 0.f, 0.f};
#pragma unroll
        for (int ks = 0; ks < 2; ++ks) {
            const int ko = ks * 32 + quad * 8;
#pragma unroll
            for (int jt = 0; jt < 4; ++jt) {
                const bf16x8 a = *(const bf16x8*)(Kb + (jt * 16 + l15) * 72 + ko);
                sf[jt] = mfma16(a, qf[ks], sf[jt]);
            }
        }

        // p = exp2(s); pack each jt-group to bf16x4 (2 dwords)
        uint2 pk[4];
#pragma unroll
        for (int jt = 0; jt < 4; ++jt) {
            f32x4 p;
#pragma unroll
            for (int i = 0; i < 4; ++i) {
                p[i] = exp2f(sf[jt][i]);
                lsum += p[i];
            }
            U2 u; u.v = __builtin_convertvector(p, bf16x4);
            pk[jt] = u.u;
        }

        // PV: B-frag P[q=l15][key=32c+quad*8+j] via dword shuffles
#pragma unroll
        for (int c = 0; c < 2; ++c) {
            const int a0 = __shfl((int)pk[2 * c].x, lA);
            const int a1 = __shfl((int)pk[2 * c].y, lA);
            const int a2 = __shfl((int)pk[2 * c].x, lB);
            const int a3 = __shfl((int)pk[2 * c].y, lB);
            const int b0 = __shfl((int)pk[2 * c + 1].x, lA);
            const int b1 = __shfl((int)pk[2 * c + 1].y, lA);
            const int b2 = __shfl((int)pk[2 * c + 1].x, lB);
            const int b3 = __shfl((int)pk[2 * c + 1].y, lB);
            U4 bu;
            bu.x[0] = hiq ? b0 : a0;
            bu.x[1] = hiq ? b1 : a1;
            bu.x[2] = hiq ? b2 : a2;
            bu.x[3] = hiq ? b3 : a3;
            const int ko = c * 32 + quad * 8;
#pragma unroll
            for (int nt = 0; nt < 4; ++nt) {
                const bf16x8 va = *(const bf16x8*)(Vb + (nt * 16 + l15) * 72 + ko);
                oacc[nt] = mfma16(va, bu.v, oacc[nt]);   // D: col=q=l15, row=d
            }
        }
    }

    // epilogue: lane (quad,l15) holds O[q=l15][d = nt*16 + quad*4 + i]
    float rs = lsum;
    rs += __shfl_xor(rs, 16);
    rs += __shfl_xor(rs, 32);
    const float inv = 1.0f / rs;
    const int bidx = bh >> 3, h = bh & 7;
    const int s = q0 + wm + l15;
    bf16_t* orow = Og + ((size_t)(bidx * SEQ + s)) * EMBED + h * HD;
#pragma unroll
    for (int nt = 0; nt < 4; ++nt) {
        bf16x4 o4;
#pragma unroll
        for (int i = 0; i < 4; ++i) o4[i] = (bf16_t)(oacc[nt][i] * inv);
        *(bf16x4*)(orow + nt * 16 + quad * 4) = o4;
    }
}

extern "C" void kernel_launch(void* const* d_in, const int* in_sizes, int n_in,
                              void* d_out, int out_size, void* d_ws, size_t ws_size,
                              hipStream_t stream)
{
    const float* x  = (const float*)d_in[0];
    const float* Wq = (const float*)d_in[1];
    const float* bq = (const float*)d_in[2];
    const float* Wk = (const float*)d_in[3];
    const float* bk = (const float*)d_in[4];
    const float* Wv = (const float*)d_in[5];
    const float* bv = (const float*)d_in[6];
    const float* Wo = (const float*)d_in[7];
    const float* bo = (const float*)d_in[8];
    float* out = (float*)d_out;

    const size_t NE = (size_t)MTOT * EMBED;
    // d_out[0..NE) bf16: xb ; d_out[NE..2NE) bf16: Qw (both dead before the
    // final fp32 out overwrites d_out). ws: Kw | Vtw | Wb-then-Ow  (24 MB).
    bf16_t* xb  = (bf16_t*)d_out;
    bf16_t* Qw  = (bf16_t*)d_out + NE;
    bf16_t* Kw  = (bf16_t*)d_ws;
    bf16_t* Vtw = Kw + NE;
    bf16_t* Ow  = Vtw + NE;
    bf16_t* Wb  = Ow;

    convert_kernel<<<dim3(64, 19), 256, 0, stream>>>(x, Wq, Wk, Wv, xb, Wb);
    gemm_gelu_kernel<0, 128><<<dim3(64, 12), 256, 0, stream>>>(
        xb, Wb, nullptr, bq, bk, bv, Qw, Kw, Vtw, nullptr);
    flash_attn_kernel<<<dim3(32, 32), 256, 0, stream>>>(Qw, Kw, Vtw, Ow);
    gemm_gelu_kernel<1, 64><<<dim3(64, 8), 256, 0, stream>>>(
        Ow, nullptr, Wo, bo, nullptr, nullptr, nullptr, nullptr, nullptr, out);
}

// Round 8
// 277.156 us; speedup vs baseline: 1.0407x; 1.0407x over previous
//
#include <hip/hip_runtime.h>
#include <hip/hip_bf16.h>

typedef __bf16 bf16_t;
typedef __bf16 bf16x4 __attribute__((ext_vector_type(4)));
typedef __bf16 bf16x8 __attribute__((ext_vector_type(8)));
typedef float  f32x4  __attribute__((ext_vector_type(4)));
typedef float  f32x8  __attribute__((ext_vector_type(8)));

#define EMBED 512
#define NH    8
#define HD    64
#define SEQ   2048
#define MTOT  8192
#define SCQ   0.18033688011112042f   // log2(e) / sqrt(64), folded into Q

__device__ __forceinline__ float gelu_f(float x) {
    return 0.5f * x * (1.0f + erff(x * 0.7071067811865475f));
}

__device__ __forceinline__ f32x4 mfma16(bf16x8 a, bf16x8 b, f32x4 c) {
    return __builtin_amdgcn_mfma_f32_16x16x32_bf16(a, b, c, 0, 0, 0);
}

// ---------------------------------------------------------------------------
// Pre-convert fp32 -> bf16: x (16 segments of 256K elems) + Wq/Wk/Wv.
// ---------------------------------------------------------------------------
__global__ __launch_bounds__(256)
void convert_kernel(const float* __restrict__ x,  const float* __restrict__ Wq,
                    const float* __restrict__ Wk, const float* __restrict__ Wv,
                    bf16_t* __restrict__ xb, bf16_t* __restrict__ wb)
{
    const int y = blockIdx.y;
    const float* src; bf16_t* dst;
    if (y < 16)      { src = x + (size_t)y * 262144; dst = xb + (size_t)y * 262144; }
    else if (y == 16){ src = Wq; dst = wb; }
    else if (y == 17){ src = Wk; dst = wb + 262144; }
    else             { src = Wv; dst = wb + 524288; }
    const int base = (blockIdx.x * 256 + threadIdx.x) * 16;
    const f32x8 a = *(const f32x8*)(src + base);
    const f32x8 b = *(const f32x8*)(src + base + 8);
    *(bf16x8*)(dst + base)     = __builtin_convertvector(a, bf16x8);
    *(bf16x8*)(dst + base + 8) = __builtin_convertvector(b, bf16x8);
}

// ---------------------------------------------------------------------------
// GEMM + bias + GELU.
// MODE 0 (X,W bf16, 128x128 tile): Q/K run operand-swapped (acc reg-run
//   along n=d), V natural (run along m=s). Epilogue round-trips the tile
//   through the (now free) staging LDS so BOTH LDS writes (bf16x4, <=2-way)
//   and global stores (bf16x8, full 128B lines completed per wave) are
//   vectorized — fixes R7's 14x HBM write amplification.
// MODE 1 (W fp32, 128x64 tile): natural, coalesced fp32 [M,EMBED] store.
// BK=64, 4 waves, register prefetch of next k-tile. LDS stride 72.
// ---------------------------------------------------------------------------
template<int MODE, int NTILE>
__global__ __launch_bounds__(256, 3)
void gemm_gelu_kernel(const bf16_t* __restrict__ Xb,
                      const bf16_t* __restrict__ Wb,   // MODE 0
                      const float*  __restrict__ Wf,   // MODE 1
                      const float*  __restrict__ Bq, const float* __restrict__ Bk,
                      const float*  __restrict__ Bv,
                      bf16_t* __restrict__ O0, bf16_t* __restrict__ O1,
                      bf16_t* __restrict__ O2, float* __restrict__ Of)
{
    constexpr int NTN = NTILE / 32;
    __shared__ __align__(16) bf16_t SMEM[128 * 72 + NTILE * 72];
    bf16_t* As = SMEM;
    bf16_t* Bs = SMEM + 128 * 72;
    const int tid  = threadIdx.x;
    const int lane = tid & 63, w = tid >> 6, quad = lane >> 4, l15 = lane & 15;
    const int m0 = blockIdx.x * 128;
    int mat, n0;
    if (MODE == 0) { mat = blockIdx.y >> 2; n0 = (blockIdx.y & 3) * NTILE; }
    else           { mat = 0;               n0 = blockIdx.y * NTILE; }
    const bf16_t* W  = (MODE == 0) ? (Wb + (size_t)mat * 262144) : nullptr;
    const float*  Bi = (MODE == 1) ? Bq : (mat == 0 ? Bq : (mat == 1 ? Bk : Bv));
    const bool swp = (MODE == 0) && (mat < 2);

    const int wr = (w >> 1) * 64;
    const int wc = (w & 1) * (NTILE / 2);
    const int srow = tid >> 3, scol = (tid & 7) * 8;

    f32x4 acc[4][NTN];
#pragma unroll
    for (int a = 0; a < 4; ++a)
#pragma unroll
        for (int b = 0; b < NTN; ++b) acc[a][b] = f32x4{0.f, 0.f, 0.f, 0.f};

    bf16x8 xp[4];
    bf16x8 wpb[NTN];
    f32x8  wpf[NTN];

#pragma unroll
    for (int it = 0; it < 4; ++it)
        xp[it] = *(const bf16x8*)(Xb + (size_t)(m0 + it * 32 + srow) * EMBED + scol);
#pragma unroll
    for (int it = 0; it < NTN; ++it) {
        const int r = it * 32 + srow;
        if (MODE == 0) wpb[it] = *(const bf16x8*)(W + (size_t)(n0 + r) * EMBED + scol);
        else           wpf[it] = *(const f32x8*)(Wf + (size_t)(n0 + r) * EMBED + scol);
    }

#pragma unroll 1
    for (int kt = 0; kt < 8; ++kt) {
        __syncthreads();
#pragma unroll
        for (int it = 0; it < 4; ++it)
            *(bf16x8*)(As + (it * 32 + srow) * 72 + scol) = xp[it];
#pragma unroll
        for (int it = 0; it < NTN; ++it) {
            const int r = it * 32 + srow;
            if (MODE == 0) *(bf16x8*)(Bs + r * 72 + scol) = wpb[it];
            else *(bf16x8*)(Bs + r * 72 + scol) = __builtin_convertvector(wpf[it], bf16x8);
        }
        if (kt < 7) {
            const int k1 = (kt + 1) * 64;
#pragma unroll
            for (int it = 0; it < 4; ++it)
                xp[it] = *(const bf16x8*)(Xb + (size_t)(m0 + it * 32 + srow) * EMBED + k1 + scol);
#pragma unroll
            for (int it = 0; it < NTN; ++it) {
                const int r = it * 32 + srow;
                if (MODE == 0) wpb[it] = *(const bf16x8*)(W + (size_t)(n0 + r) * EMBED + k1 + scol);
                else           wpf[it] = *(const f32x8*)(Wf + (size_t)(n0 + r) * EMBED + k1 + scol);
            }
        }
        __syncthreads();
#pragma unroll
        for (int ks = 0; ks < 2; ++ks) {
            const int ko = (ks * 4 + quad) * 8;
            bf16x8 av[4], bv[NTN];
#pragma unroll
            for (int mt = 0; mt < 4; ++mt)
                av[mt] = *(const bf16x8*)(As + (wr + mt * 16 + l15) * 72 + ko);
#pragma unroll
            for (int nt = 0; nt < NTN; ++nt)
                bv[nt] = *(const bf16x8*)(Bs + (wc + nt * 16 + l15) * 72 + ko);
            if (swp) {
#pragma unroll
                for (int a = 0; a < NTN; ++a)
#pragma unroll
                    for (int b = 0; b < 4; ++b)
                        acc[a][b] = mfma16(bv[a], av[b], acc[a][b]);   // n=row-run, m=col
            } else {
#pragma unroll
                for (int a = 0; a < 4; ++a)
#pragma unroll
                    for (int b = 0; b < NTN; ++b)
                        acc[a][b] = mfma16(av[a], bv[b], acc[a][b]);   // m=row-run, n=col
            }
        }
    }

    if (MODE == 0) {
        // ---- LDS-transposed epilogue.  T is 128x136 bf16 (34.8 KB) in SMEM.
        bf16_t* T = SMEM;
        __syncthreads();   // last compute's LDS reads done
        if (swp) {
            // acc[at][bt]: n = wc+at*16+quad*4+i, m = wr+bt*16+l15 -> T[m][n]
            const float scl = (mat == 0) ? SCQ : 1.0f;
#pragma unroll
            for (int at = 0; at < 4; ++at) {
                const int nb = wc + at * 16 + quad * 4;
                const f32x4 b4 = *(const f32x4*)(Bi + n0 + nb);
#pragma unroll
                for (int bt = 0; bt < 4; ++bt) {
                    const int m = wr + bt * 16 + l15;
                    bf16x4 pk;
#pragma unroll
                    for (int i = 0; i < 4; ++i)
                        pk[i] = (bf16_t)(gelu_f(acc[at][bt][i] + b4[i]) * scl);
                    *(bf16x4*)(T + m * 136 + nb) = pk;
                }
            }
        } else {
            // acc[mt][nt]: m = wr+mt*16+quad*4+i, n = wc+nt*16+l15 -> T[n][m]
#pragma unroll
            for (int mt = 0; mt < 4; ++mt) {
                const int mloc = wr + mt * 16 + quad * 4;
#pragma unroll
                for (int nt = 0; nt < 4; ++nt) {
                    const int nloc = wc + nt * 16 + l15;
                    const float bs = Bi[n0 + nloc];
                    bf16x4 pk;
#pragma unroll
                    for (int i = 0; i < 4; ++i)
                        pk[i] = (bf16_t)gelu_f(acc[mt][nt][i] + bs);
                    *(bf16x4*)(T + nloc * 136 + mloc) = pk;
                }
            }
        }
        __syncthreads();
        const int row = tid & 127, half = tid >> 7;
        if (mat < 2) {
            // T[m(s)][n(d)] -> bf16x8 along d; wave covers 64 s-rows x 16B,
            // 8 stores complete each head-row's 128B line.
            bf16_t* O = (mat == 0) ? O0 : O1;
            const int m = m0 + row, bb = m >> 11, s = m & (SEQ - 1);
#pragma unroll
            for (int j = 0; j < 8; ++j) {
                const int dl = half * 64 + j * 8;
                const bf16x8 v = *(const bf16x8*)(T + row * 136 + dl);
                const int fc = n0 + dl, h = fc >> 6, d = fc & 63;
                *(bf16x8*)(O + (((size_t)(bb * NH + h)) * SEQ + s) * HD + d) = v;
            }
        } else {
            // T[n(d)][m(s)] -> bf16x8 along s into [B,H,D,S]
            const int fc = n0 + row, h = fc >> 6, d = fc & 63;
#pragma unroll
            for (int j = 0; j < 8; ++j) {
                const int ml = half * 64 + j * 8;
                const bf16x8 v = *(const bf16x8*)(T + row * 136 + ml);
                const int m = m0 + ml, bb = m >> 11, s0 = m & (SEQ - 1);
                *(bf16x8*)(O2 + ((size_t)(bb * NH + h) * HD + d) * SEQ + s0) = v;
            }
        }
    } else {
        // fp32 natural store, coalesced 64B per quad-row
#pragma unroll
        for (int mt = 0; mt < 4; ++mt) {
            const int mb = m0 + wr + mt * 16 + quad * 4;
#pragma unroll
            for (int nt = 0; nt < NTN; ++nt) {
                const int fc = n0 + wc + nt * 16 + l15;
                const float bs = Bi[fc];
#pragma unroll
                for (int i = 0; i < 4; ++i)
                    Of[(size_t)(mb + i) * EMBED + fc] = gelu_f(acc[mt][nt][i] + bs);
            }
        }
    }
}

// ---------------------------------------------------------------------------
// Flash attention (R6 version — 82 us known-good).  Q pre-scaled by
// log2(e)/8 => p = exp2(s - 8) (exact math, shift cancels in O/l).
// S^T = K*Q^T gives P[q=l15][key=quad*4+i]; P round-trips a per-wave LDS
// buffer (no barrier); PV reads P back as A-fragments.
// Block = 64 Q rows, KV tile 64 double-buffered, grid 32x32.
// ---------------------------------------------------------------------------
__global__ __launch_bounds__(256, 3)
void flash_attn_kernel(const bf16_t* __restrict__ Q,
                       const bf16_t* __restrict__ K,
                       const bf16_t* __restrict__ Vt,
                       bf16_t* __restrict__ Og)
{
    __shared__ __align__(16) bf16_t Ks[2][64 * 72];
    __shared__ __align__(16) bf16_t Vs[2][64 * 72];
    __shared__ __align__(16) bf16_t Ps[4][16 * 72];

    const int tid  = threadIdx.x;
    const int lane = tid & 63, w = tid >> 6, quad = lane >> 4, l15 = lane & 15;
    const int bh = blockIdx.y;
    const int q0 = blockIdx.x * 64;
    const size_t baseQK = (size_t)bh * SEQ * HD;
    const size_t baseV  = (size_t)bh * HD * SEQ;
    const int wm = w * 16;

    bf16x8 qf[2];
#pragma unroll
    for (int ks = 0; ks < 2; ++ks)
        qf[ks] = *(const bf16x8*)(Q + baseQK + (size_t)(q0 + wm + l15) * HD + ks * 32 + quad * 8);

    float lsum = 0.f;
    f32x4 oacc[4];
#pragma unroll
    for (int nt = 0; nt < 4; ++nt) oacc[nt] = f32x4{0.f, 0.f, 0.f, 0.f};

    bf16_t* Pw = Ps[w];
    const int r0 = tid >> 3, c0 = (tid & 7) * 8;
    bf16x8 kr0, kr1, vr0, vr1;

    kr0 = *(const bf16x8*)(K + baseQK + (size_t)r0 * HD + c0);
    kr1 = *(const bf16x8*)(K + baseQK + (size_t)(r0 + 32) * HD + c0);
    vr0 = *(const bf16x8*)(Vt + baseV + (size_t)r0 * SEQ + c0);
    vr1 = *(const bf16x8*)(Vt + baseV + (size_t)(r0 + 32) * SEQ + c0);
    *(bf16x8*)(Ks[0] + r0 * 72 + c0)        = kr0;
    *(bf16x8*)(Ks[0] + (r0 + 32) * 72 + c0) = kr1;
    *(bf16x8*)(Vs[0] + r0 * 72 + c0)        = vr0;
    *(bf16x8*)(Vs[0] + (r0 + 32) * 72 + c0) = vr1;
    kr0 = *(const bf16x8*)(K + baseQK + (size_t)(64 + r0) * HD + c0);
    kr1 = *(const bf16x8*)(K + baseQK + (size_t)(64 + r0 + 32) * HD + c0);
    vr0 = *(const bf16x8*)(Vt + baseV + (size_t)r0 * SEQ + 64 + c0);
    vr1 = *(const bf16x8*)(Vt + baseV + (size_t)(r0 + 32) * SEQ + 64 + c0);

#pragma unroll 1
    for (int t = 0; t < 32; ++t) {
        __syncthreads();
        if (t + 1 < 32) {
            bf16_t* Kn = Ks[(t + 1) & 1];
            bf16_t* Vn = Vs[(t + 1) & 1];
            *(bf16x8*)(Kn + r0 * 72 + c0)        = kr0;
            *(bf16x8*)(Kn + (r0 + 32) * 72 + c0) = kr1;
            *(bf16x8*)(Vn + r0 * 72 + c0)        = vr0;
            *(bf16x8*)(Vn + (r0 + 32) * 72 + c0) = vr1;
        }
        if (t + 2 < 32) {
            const int kv = (t + 2) * 64;
            kr0 = *(const bf16x8*)(K + baseQK + (size_t)(kv + r0) * HD + c0);
            kr1 = *(const bf16x8*)(K + baseQK + (size_t)(kv + r0 + 32) * HD + c0);
            vr0 = *(const bf16x8*)(Vt + baseV + (size_t)r0 * SEQ + kv + c0);
            vr1 = *(const bf16x8*)(Vt + baseV + (size_t)(r0 + 32) * SEQ + kv + c0);
        }

        const bf16_t* Kb = Ks[t & 1];
        const bf16_t* Vb = Vs[t & 1];

        f32x4 sf[4];
#pragma unroll
        for (int jt = 0; jt < 4; ++jt) sf[jt] = f32x4{0.f, 0.f, 0.f, 0.f};
#pragma unroll
        for (int ks = 0; ks < 2; ++ks) {
            const int ko = ks * 32 + quad * 8;
#pragma unroll
            for (int jt = 0; jt < 4; ++jt) {
                const bf16x8 a = *(const bf16x8*)(Kb + (jt * 16 + l15) * 72 + ko);
                sf[jt] = mfma16(a, qf[ks], sf[jt]);
            }
        }

#pragma unroll
        for (int jt = 0; jt < 4; ++jt) {
#pragma unroll
            for (int i = 0; i < 4; ++i) {
                const float pv = exp2f(sf[jt][i] - 8.f);
                sf[jt][i] = pv;
                lsum += pv;
            }
            const bf16x4 pk = __builtin_convertvector(sf[jt], bf16x4);
            *(bf16x4*)(Pw + l15 * 72 + jt * 16 + quad * 4) = pk;
        }

#pragma unroll
        for (int c = 0; c < 2; ++c) {
            const int ko = c * 32 + quad * 8;
            const bf16x8 a = *(const bf16x8*)(Pw + l15 * 72 + ko);
#pragma unroll
            for (int nt = 0; nt < 4; ++nt) {
                const bf16x8 b = *(const bf16x8*)(Vb + (nt * 16 + l15) * 72 + ko);
                oacc[nt] = mfma16(a, b, oacc[nt]);
            }
        }
    }

    float rs = lsum;
    rs += __shfl_xor(rs, 16);
    rs += __shfl_xor(rs, 32);
    const int bidx = bh >> 3, h = bh & 7;
    float lf[4];
#pragma unroll
    for (int i = 0; i < 4; ++i)
        lf[i] = __shfl(rs, (lane & 48) | (quad * 4 + i));
#pragma unroll
    for (int nt = 0; nt < 4; ++nt)
#pragma unroll
        for (int i = 0; i < 4; ++i) {
            const int s = q0 + wm + quad * 4 + i;
            const int d = nt * 16 + l15;
            Og[((size_t)(bidx * SEQ + s)) * EMBED + h * HD + d] =
                (bf16_t)(oacc[nt][i] / lf[i]);
        }
}

extern "C" void kernel_launch(void* const* d_in, const int* in_sizes, int n_in,
                              void* d_out, int out_size, void* d_ws, size_t ws_size,
                              hipStream_t stream)
{
    const float* x  = (const float*)d_in[0];
    const float* Wq = (const float*)d_in[1];
    const float* bq = (const float*)d_in[2];
    const float* Wk = (const float*)d_in[3];
    const float* bk = (const float*)d_in[4];
    const float* Wv = (const float*)d_in[5];
    const float* bv = (const float*)d_in[6];
    const float* Wo = (const float*)d_in[7];
    const float* bo = (const float*)d_in[8];
    float* out = (float*)d_out;

    const size_t NE = (size_t)MTOT * EMBED;
    bf16_t* xb  = (bf16_t*)d_out;
    bf16_t* Qw  = (bf16_t*)d_out + NE;
    bf16_t* Kw  = (bf16_t*)d_ws;
    bf16_t* Vtw = Kw + NE;
    bf16_t* Ow  = Vtw + NE;
    bf16_t* Wb  = Ow;

    convert_kernel<<<dim3(64, 19), 256, 0, stream>>>(x, Wq, Wk, Wv, xb, Wb);
    gemm_gelu_kernel<0, 128><<<dim3(64, 12), 256, 0, stream>>>(
        xb, Wb, nullptr, bq, bk, bv, Qw, Kw, Vtw, nullptr);
    flash_attn_kernel<<<dim3(32, 32), 256, 0, stream>>>(Qw, Kw, Vtw, Ow);
    gemm_gelu_kernel<1, 64><<<dim3(64, 8), 256, 0, stream>>>(
        Ow, nullptr, Wo, bo, nullptr, nullptr, nullptr, nullptr, nullptr, out);
}

// Round 9
// 276.226 us; speedup vs baseline: 1.0442x; 1.0034x over previous
//
#include <hip/hip_runtime.h>
#include <hip/hip_bf16.h>

typedef __bf16 bf16_t;
typedef __bf16 bf16x4 __attribute__((ext_vector_type(4)));
typedef __bf16 bf16x8 __attribute__((ext_vector_type(8)));
typedef float  f32x4  __attribute__((ext_vector_type(4)));
typedef float  f32x8  __attribute__((ext_vector_type(8)));

#define EMBED 512
#define NH    8
#define HD    64
#define SEQ   2048
#define MTOT  8192
#define SCQ   0.18033688011112042f   // log2(e) / sqrt(64), folded into Q

__device__ __forceinline__ float gelu_f(float x) {
    return 0.5f * x * (1.0f + erff(x * 0.7071067811865475f));
}

__device__ __forceinline__ f32x4 mfma16(bf16x8 a, bf16x8 b, f32x4 c) {
    return __builtin_amdgcn_mfma_f32_16x16x32_bf16(a, b, c, 0, 0, 0);
}

// ---------------------------------------------------------------------------
// Pre-convert fp32 -> bf16: x (16 segments of 256K elems) + Wq/Wk/Wv.
// ---------------------------------------------------------------------------
__global__ __launch_bounds__(256)
void convert_kernel(const float* __restrict__ x,  const float* __restrict__ Wq,
                    const float* __restrict__ Wk, const float* __restrict__ Wv,
                    bf16_t* __restrict__ xb, bf16_t* __restrict__ wb)
{
    const int y = blockIdx.y;
    const float* src; bf16_t* dst;
    if (y < 16)      { src = x + (size_t)y * 262144; dst = xb + (size_t)y * 262144; }
    else if (y == 16){ src = Wq; dst = wb; }
    else if (y == 17){ src = Wk; dst = wb + 262144; }
    else             { src = Wv; dst = wb + 524288; }
    const int base = (blockIdx.x * 256 + threadIdx.x) * 16;
    const f32x8 a = *(const f32x8*)(src + base);
    const f32x8 b = *(const f32x8*)(src + base + 8);
    *(bf16x8*)(dst + base)     = __builtin_convertvector(a, bf16x8);
    *(bf16x8*)(dst + base + 8) = __builtin_convertvector(b, bf16x8);
}

// ---------------------------------------------------------------------------
// GEMM + bias + GELU.
// MODE 0 (X,W bf16, 128x128 tile): Q/K operand-swapped, V natural; epilogue
//   goes acc -> LDS tile T (bf16x4) -> global with LANE-CONTIGUOUS bursts:
//   Q/K: each wave-instr stores 1 KB contiguous (8 s-rows x 64-d head row);
//   V:   each wave-instr stores 4 x 256-B contiguous (h,d)-row segments.
//   (R7/R8 post-mortem: per-instruction 64-line scatter of 8-16B partials
//    caused 13.5x HBM write amplification; contiguity must be across lanes.)
// MODE 1 (W fp32, 128x64 tile): natural, coalesced fp32 [M,EMBED] store.
// BK=64, 4 waves, register prefetch of next k-tile. LDS stride 72.
// ---------------------------------------------------------------------------
template<int MODE, int NTILE>
__global__ __launch_bounds__(256, 3)
void gemm_gelu_kernel(const bf16_t* __restrict__ Xb,
                      const bf16_t* __restrict__ Wb,   // MODE 0
                      const float*  __restrict__ Wf,   // MODE 1
                      const float*  __restrict__ Bq, const float* __restrict__ Bk,
                      const float*  __restrict__ Bv,
                      bf16_t* __restrict__ O0, bf16_t* __restrict__ O1,
                      bf16_t* __restrict__ O2, float* __restrict__ Of)
{
    constexpr int NTN = NTILE / 32;
    __shared__ __align__(16) bf16_t SMEM[128 * 72 + NTILE * 72];
    bf16_t* As = SMEM;
    bf16_t* Bs = SMEM + 128 * 72;
    const int tid  = threadIdx.x;
    const int lane = tid & 63, w = tid >> 6, quad = lane >> 4, l15 = lane & 15;
    const int m0 = blockIdx.x * 128;
    int mat, n0;
    if (MODE == 0) { mat = blockIdx.y >> 2; n0 = (blockIdx.y & 3) * NTILE; }
    else           { mat = 0;               n0 = blockIdx.y * NTILE; }
    const bf16_t* W  = (MODE == 0) ? (Wb + (size_t)mat * 262144) : nullptr;
    const float*  Bi = (MODE == 1) ? Bq : (mat == 0 ? Bq : (mat == 1 ? Bk : Bv));
    const bool swp = (MODE == 0) && (mat < 2);

    const int wr = (w >> 1) * 64;
    const int wc = (w & 1) * (NTILE / 2);
    const int srow = tid >> 3, scol = (tid & 7) * 8;

    f32x4 acc[4][NTN];
#pragma unroll
    for (int a = 0; a < 4; ++a)
#pragma unroll
        for (int b = 0; b < NTN; ++b) acc[a][b] = f32x4{0.f, 0.f, 0.f, 0.f};

    bf16x8 xp[4];
    bf16x8 wpb[NTN];
    f32x8  wpf[NTN];

#pragma unroll
    for (int it = 0; it < 4; ++it)
        xp[it] = *(const bf16x8*)(Xb + (size_t)(m0 + it * 32 + srow) * EMBED + scol);
#pragma unroll
    for (int it = 0; it < NTN; ++it) {
        const int r = it * 32 + srow;
        if (MODE == 0) wpb[it] = *(const bf16x8*)(W + (size_t)(n0 + r) * EMBED + scol);
        else           wpf[it] = *(const f32x8*)(Wf + (size_t)(n0 + r) * EMBED + scol);
    }

#pragma unroll 1
    for (int kt = 0; kt < 8; ++kt) {
        __syncthreads();
#pragma unroll
        for (int it = 0; it < 4; ++it)
            *(bf16x8*)(As + (it * 32 + srow) * 72 + scol) = xp[it];
#pragma unroll
        for (int it = 0; it < NTN; ++it) {
            const int r = it * 32 + srow;
            if (MODE == 0) *(bf16x8*)(Bs + r * 72 + scol) = wpb[it];
            else *(bf16x8*)(Bs + r * 72 + scol) = __builtin_convertvector(wpf[it], bf16x8);
        }
        if (kt < 7) {
            const int k1 = (kt + 1) * 64;
#pragma unroll
            for (int it = 0; it < 4; ++it)
                xp[it] = *(const bf16x8*)(Xb + (size_t)(m0 + it * 32 + srow) * EMBED + k1 + scol);
#pragma unroll
            for (int it = 0; it < NTN; ++it) {
                const int r = it * 32 + srow;
                if (MODE == 0) wpb[it] = *(const bf16x8*)(W + (size_t)(n0 + r) * EMBED + k1 + scol);
                else           wpf[it] = *(const f32x8*)(Wf + (size_t)(n0 + r) * EMBED + k1 + scol);
            }
        }
        __syncthreads();
#pragma unroll
        for (int ks = 0; ks < 2; ++ks) {
            const int ko = (ks * 4 + quad) * 8;
            bf16x8 av[4], bv[NTN];
#pragma unroll
            for (int mt = 0; mt < 4; ++mt)
                av[mt] = *(const bf16x8*)(As + (wr + mt * 16 + l15) * 72 + ko);
#pragma unroll
            for (int nt = 0; nt < NTN; ++nt)
                bv[nt] = *(const bf16x8*)(Bs + (wc + nt * 16 + l15) * 72 + ko);
            if (swp) {
#pragma unroll
                for (int a = 0; a < NTN; ++a)
#pragma unroll
                    for (int b = 0; b < 4; ++b)
                        acc[a][b] = mfma16(bv[a], av[b], acc[a][b]);   // n=row-run, m=col
            } else {
#pragma unroll
                for (int a = 0; a < 4; ++a)
#pragma unroll
                    for (int b = 0; b < NTN; ++b)
                        acc[a][b] = mfma16(av[a], bv[b], acc[a][b]);   // m=row-run, n=col
            }
        }
    }

    if (MODE == 0) {
        // ---- LDS-transposed epilogue.  T is 128x136 bf16 (34.8 KB) in SMEM.
        bf16_t* T = SMEM;
        __syncthreads();   // last compute's LDS reads done
        if (swp) {
            // acc[at][bt]: n = wc+at*16+quad*4+i, m = wr+bt*16+l15 -> T[m][n]
            const float scl = (mat == 0) ? SCQ : 1.0f;
#pragma unroll
            for (int at = 0; at < 4; ++at) {
                const int nb = wc + at * 16 + quad * 4;
                const f32x4 b4 = *(const f32x4*)(Bi + n0 + nb);
#pragma unroll
                for (int bt = 0; bt < 4; ++bt) {
                    const int m = wr + bt * 16 + l15;
                    bf16x4 pk;
#pragma unroll
                    for (int i = 0; i < 4; ++i)
                        pk[i] = (bf16_t)(gelu_f(acc[at][bt][i] + b4[i]) * scl);
                    *(bf16x4*)(T + m * 136 + nb) = pk;
                }
            }
        } else {
            // acc[mt][nt]: m = wr+mt*16+quad*4+i, n = wc+nt*16+l15 -> T[n][m]
#pragma unroll
            for (int mt = 0; mt < 4; ++mt) {
                const int mloc = wr + mt * 16 + quad * 4;
#pragma unroll
                for (int nt = 0; nt < 4; ++nt) {
                    const int nloc = wc + nt * 16 + l15;
                    const float bs = Bi[n0 + nloc];
                    bf16x4 pk;
#pragma unroll
                    for (int i = 0; i < 4; ++i)
                        pk[i] = (bf16_t)gelu_f(acc[mt][nt][i] + bs);
                    *(bf16x4*)(T + nloc * 136 + mloc) = pk;
                }
            }
        }
        __syncthreads();
        const int w8 = w * 8;
        if (mat < 2) {
            // Q/K: 32 chunks of 1 KB contiguous. chunk -> (head-half hh,
            // s-group sg); lane -> (s-row = lane>>3, d-chunk = (lane&7)*8).
            bf16_t* O = (mat == 0) ? O0 : O1;
#pragma unroll
            for (int it = 0; it < 8; ++it) {
                const int chunk = w8 + it;            // 0..31
                const int hh = chunk >> 4, sg = chunk & 15;
                const int sr = lane >> 3, dc = (lane & 7) * 8;
                const int m = m0 + sg * 8 + sr;
                const int bb = m >> 11, s = m & (SEQ - 1);
                const int h = (n0 + hh * 64) >> 6;
                const bf16x8 v = *(const bf16x8*)(T + (sg * 8 + sr) * 136 + hh * 64 + dc);
                *(bf16x8*)(O + (((size_t)(bb * NH + h)) * SEQ + s) * HD + dc) = v;
            }
        } else {
            // V: 32 chunks of 4 (h,d)-rows x 256-B contiguous s-segments.
            const int bb = m0 >> 11, sbase = m0 & (SEQ - 1);
#pragma unroll
            for (int it = 0; it < 8; ++it) {
                const int chunk = w8 + it;            // 0..31
                const int r = lane >> 4, sc = (lane & 15) * 8;
                const int nloc = chunk * 4 + r;
                const int fc = n0 + nloc, h = fc >> 6, d = fc & 63;
                const bf16x8 v = *(const bf16x8*)(T + nloc * 136 + sc);
                *(bf16x8*)(O2 + ((size_t)(bb * NH + h) * HD + d) * SEQ + sbase + sc) = v;
            }
        }
    } else {
        // fp32 natural store, coalesced 64B per quad-row
#pragma unroll
        for (int mt = 0; mt < 4; ++mt) {
            const int mb = m0 + wr + mt * 16 + quad * 4;
#pragma unroll
            for (int nt = 0; nt < NTN; ++nt) {
                const int fc = n0 + wc + nt * 16 + l15;
                const float bs = Bi[fc];
#pragma unroll
                for (int i = 0; i < 4; ++i)
                    Of[(size_t)(mb + i) * EMBED + fc] = gelu_f(acc[mt][nt][i] + bs);
            }
        }
    }
}

// ---------------------------------------------------------------------------
// Flash attention (R6 version — 82 us known-good).  Q pre-scaled by
// log2(e)/8 => p = exp2(s - 8) (exact math, shift cancels in O/l).
// S^T = K*Q^T gives P[q=l15][key=quad*4+i]; P round-trips a per-wave LDS
// buffer (no barrier); PV reads P back as A-fragments.
// Block = 64 Q rows, KV tile 64 double-buffered, grid 32x32.
// ---------------------------------------------------------------------------
__global__ __launch_bounds__(256, 3)
void flash_attn_kernel(const bf16_t* __restrict__ Q,
                       const bf16_t* __restrict__ K,
                       const bf16_t* __restrict__ Vt,
                       bf16_t* __restrict__ Og)
{
    __shared__ __align__(16) bf16_t Ks[2][64 * 72];
    __shared__ __align__(16) bf16_t Vs[2][64 * 72];
    __shared__ __align__(16) bf16_t Ps[4][16 * 72];

    const int tid  = threadIdx.x;
    const int lane = tid & 63, w = tid >> 6, quad = lane >> 4, l15 = lane & 15;
    const int bh = blockIdx.y;
    const int q0 = blockIdx.x * 64;
    const size_t baseQK = (size_t)bh * SEQ * HD;
    const size_t baseV  = (size_t)bh * HD * SEQ;
    const int wm = w * 16;

    bf16x8 qf[2];
#pragma unroll
    for (int ks = 0; ks < 2; ++ks)
        qf[ks] = *(const bf16x8*)(Q + baseQK + (size_t)(q0 + wm + l15) * HD + ks * 32 + quad * 8);

    float lsum = 0.f;
    f32x4 oacc[4];
#pragma unroll
    for (int nt = 0; nt < 4; ++nt) oacc[nt] = f32x4{0.f, 0.f, 0.f, 0.f};

    bf16_t* Pw = Ps[w];
    const int r0 = tid >> 3, c0 = (tid & 7) * 8;
    bf16x8 kr0, kr1, vr0, vr1;

    kr0 = *(const bf16x8*)(K + baseQK + (size_t)r0 * HD + c0);
    kr1 = *(const bf16x8*)(K + baseQK + (size_t)(r0 + 32) * HD + c0);
    vr0 = *(const bf16x8*)(Vt + baseV + (size_t)r0 * SEQ + c0);
    vr1 = *(const bf16x8*)(Vt + baseV + (size_t)(r0 + 32) * SEQ + c0);
    *(bf16x8*)(Ks[0] + r0 * 72 + c0)        = kr0;
    *(bf16x8*)(Ks[0] + (r0 + 32) * 72 + c0) = kr1;
    *(bf16x8*)(Vs[0] + r0 * 72 + c0)        = vr0;
    *(bf16x8*)(Vs[0] + (r0 + 32) * 72 + c0) = vr1;
    kr0 = *(const bf16x8*)(K + baseQK + (size_t)(64 + r0) * HD + c0);
    kr1 = *(const bf16x8*)(K + baseQK + (size_t)(64 + r0 + 32) * HD + c0);
    vr0 = *(const bf16x8*)(Vt + baseV + (size_t)r0 * SEQ + 64 + c0);
    vr1 = *(const bf16x8*)(Vt + baseV + (size_t)(r0 + 32) * SEQ + 64 + c0);

#pragma unroll 1
    for (int t = 0; t < 32; ++t) {
        __syncthreads();
        if (t + 1 < 32) {
            bf16_t* Kn = Ks[(t + 1) & 1];
            bf16_t* Vn = Vs[(t + 1) & 1];
            *(bf16x8*)(Kn + r0 * 72 + c0)        = kr0;
            *(bf16x8*)(Kn + (r0 + 32) * 72 + c0) = kr1;
            *(bf16x8*)(Vn + r0 * 72 + c0)        = vr0;
            *(bf16x8*)(Vn + (r0 + 32) * 72 + c0) = vr1;
        }
        if (t + 2 < 32) {
            const int kv = (t + 2) * 64;
            kr0 = *(const bf16x8*)(K + baseQK + (size_t)(kv + r0) * HD + c0);
            kr1 = *(const bf16x8*)(K + baseQK + (size_t)(kv + r0 + 32) * HD + c0);
            vr0 = *(const bf16x8*)(Vt + baseV + (size_t)r0 * SEQ + kv + c0);
            vr1 = *(const bf16x8*)(Vt + baseV + (size_t)(r0 + 32) * SEQ + kv + c0);
        }

        const bf16_t* Kb = Ks[t & 1];
        const bf16_t* Vb = Vs[t & 1];

        f32x4 sf[4];
#pragma unroll
        for (int jt = 0; jt < 4; ++jt) sf[jt] = f32x4{0.f, 0.f, 0.f, 0.f};
#pragma unroll
        for (int ks = 0; ks < 2; ++ks) {
            const int ko = ks * 32 + quad * 8;
#pragma unroll
            for (int jt = 0; jt < 4; ++jt) {
                const bf16x8 a = *(const bf16x8*)(Kb + (jt * 16 + l15) * 72 + ko);
                sf[jt] = mfma16(a, qf[ks], sf[jt]);
            }
        }

#pragma unroll
        for (int jt = 0; jt < 4; ++jt) {
#pragma unroll
            for (int i = 0; i < 4; ++i) {
                const float pv = exp2f(sf[jt][i] - 8.f);
                sf[jt][i] = pv;
                lsum += pv;
            }
            const bf16x4 pk = __builtin_convertvector(sf[jt], bf16x4);
            *(bf16x4*)(Pw + l15 * 72 + jt * 16 + quad * 4) = pk;
        }

#pragma unroll
        for (int c = 0; c < 2; ++c) {
            const int ko = c * 32 + quad * 8;
            const bf16x8 a = *(const bf16x8*)(Pw + l15 * 72 + ko);
#pragma unroll
            for (int nt = 0; nt < 4; ++nt) {
                const bf16x8 b = *(const bf16x8*)(Vb + (nt * 16 + l15) * 72 + ko);
                oacc[nt] = mfma16(a, b, oacc[nt]);
            }
        }
    }

    float rs = lsum;
    rs += __shfl_xor(rs, 16);
    rs += __shfl_xor(rs, 32);
    const int bidx = bh >> 3, h = bh & 7;
    float lf[4];
#pragma unroll
    for (int i = 0; i < 4; ++i)
        lf[i] = __shfl(rs, (lane & 48) | (quad * 4 + i));
#pragma unroll
    for (int nt = 0; nt < 4; ++nt)
#pragma unroll
        for (int i = 0; i < 4; ++i) {
            const int s = q0 + wm + quad * 4 + i;
            const int d = nt * 16 + l15;
            Og[((size_t)(bidx * SEQ + s)) * EMBED + h * HD + d] =
                (bf16_t)(oacc[nt][i] / lf[i]);
        }
}

extern "C" void kernel_launch(void* const* d_in, const int* in_sizes, int n_in,
                              void* d_out, int out_size, void* d_ws, size_t ws_size,
                              hipStream_t stream)
{
    const float* x  = (const float*)d_in[0];
    const float* Wq = (const float*)d_in[1];
    const float* bq = (const float*)d_in[2];
    const float* Wk = (const float*)d_in[3];
    const float* bk = (const float*)d_in[4];
    const float* Wv = (const float*)d_in[5];
    const float* bv = (const float*)d_in[6];
    const float* Wo = (const float*)d_in[7];
    const float* bo = (const float*)d_in[8];
    float* out = (float*)d_out;

    const size_t NE = (size_t)MTOT * EMBED;
    bf16_t* xb  = (bf16_t*)d_out;
    bf16_t* Qw  = (bf16_t*)d_out + NE;
    bf16_t* Kw  = (bf16_t*)d_ws;
    bf16_t* Vtw = Kw + NE;
    bf16_t* Ow  = Vtw + NE;
    bf16_t* Wb  = Ow;

    convert_kernel<<<dim3(64, 19), 256, 0, stream>>>(x, Wq, Wk, Wv, xb, Wb);
    gemm_gelu_kernel<0, 128><<<dim3(64, 12), 256, 0, stream>>>(
        xb, Wb, nullptr, bq, bk, bv, Qw, Kw, Vtw, nullptr);
    flash_attn_kernel<<<dim3(32, 32), 256, 0, stream>>>(Qw, Kw, Vtw, Ow);
    gemm_gelu_kernel<1, 64><<<dim3(64, 8), 256, 0, stream>>>(
        Ow, nullptr, Wo, bo, nullptr, nullptr, nullptr, nullptr, nullptr, out);
}

// Round 10
// 199.265 us; speedup vs baseline: 1.4475x; 1.3862x over previous
//
#include <hip/hip_runtime.h>
#include <hip/hip_bf16.h>

typedef __bf16 bf16_t;
typedef __bf16 bf16x4 __attribute__((ext_vector_type(4)));
typedef __bf16 bf16x8 __attribute__((ext_vector_type(8)));
typedef float  f32x4  __attribute__((ext_vector_type(4)));
typedef float  f32x8  __attribute__((ext_vector_type(8)));

#define EMBED 512
#define NH    8
#define HD    64
#define SEQ   2048
#define MTOT  8192
#define SCQ   0.18033688011112042f   // log2(e) / sqrt(64), folded into Q

__device__ __forceinline__ float gelu_f(float x) {
    return 0.5f * x * (1.0f + erff(x * 0.7071067811865475f));
}

__device__ __forceinline__ f32x4 mfma16(bf16x8 a, bf16x8 b, f32x4 c) {
    return __builtin_amdgcn_mfma_f32_16x16x32_bf16(a, b, c, 0, 0, 0);
}

// ---------------------------------------------------------------------------
// Pre-convert fp32 -> bf16: x (16 segments of 256K elems) + Wq/Wk/Wv.
// ---------------------------------------------------------------------------
__global__ __launch_bounds__(256)
void convert_kernel(const float* __restrict__ x,  const float* __restrict__ Wq,
                    const float* __restrict__ Wk, const float* __restrict__ Wv,
                    bf16_t* __restrict__ xb, bf16_t* __restrict__ wb)
{
    const int y = blockIdx.y;
    const float* src; bf16_t* dst;
    if (y < 16)      { src = x + (size_t)y * 262144; dst = xb + (size_t)y * 262144; }
    else if (y == 16){ src = Wq; dst = wb; }
    else if (y == 17){ src = Wk; dst = wb + 262144; }
    else             { src = Wv; dst = wb + 524288; }
    const int base = (blockIdx.x * 256 + threadIdx.x) * 16;
    const f32x8 a = *(const f32x8*)(src + base);
    const f32x8 b = *(const f32x8*)(src + base + 8);
    *(bf16x8*)(dst + base)     = __builtin_convertvector(a, bf16x8);
    *(bf16x8*)(dst + base + 8) = __builtin_convertvector(b, bf16x8);
}

// ---------------------------------------------------------------------------
// GEMM + bias + GELU — orientation is now COMPILE-TIME (R7-R9 post-mortem:
// the runtime swp branch coincided with VGPR_Count=84 (< the 96+ the kernel
// needs) and ~330 MB phantom HBM writes ≈ acc spilled to scratch).
// MODE 0: Q,K (mat = y>>2), operand-SWAPPED MFMA (acc reg-run along n=d);
//         epilogue: acc -> LDS T[m][n] -> 1 KB lane-contiguous bursts.
// MODE 1: V, natural MFMA (run along m=s); acc -> T[n][m] -> 256B bursts
//         into [B,H,D,S].
// MODE 2: out-proj, W fp32, natural, coalesced fp32 [M,EMBED] store.
// 128 x NTILE tile, BK=64, 4 waves, register prefetch of next k-tile.
// Padded LDS stride 72 (144B; <=2-way bank conflicts = free).
// ---------------------------------------------------------------------------
template<int MODE, int NTILE>
__global__ __launch_bounds__(256, 3)
void gemm_gelu_kernel(const bf16_t* __restrict__ Xb,
                      const bf16_t* __restrict__ Wb,   // MODE 0/1
                      const float*  __restrict__ Wf,   // MODE 2
                      const float*  __restrict__ B0,   // bias (bq / bv / bo)
                      const float*  __restrict__ B1,   // bias bk (MODE 0)
                      bf16_t* __restrict__ O0, bf16_t* __restrict__ O1,
                      bf16_t* __restrict__ O2, float* __restrict__ Of)
{
    constexpr int NTN = NTILE / 32;
    __shared__ __align__(16) bf16_t SMEM[128 * 72 + NTILE * 72];
    bf16_t* As = SMEM;
    bf16_t* Bs = SMEM + 128 * 72;
    const int tid  = threadIdx.x;
    const int lane = tid & 63, w = tid >> 6, quad = lane >> 4, l15 = lane & 15;
    const int m0 = blockIdx.x * 128;
    int mat, n0;
    if (MODE == 0) { mat = blockIdx.y >> 2; n0 = (blockIdx.y & 3) * 128; }
    else           { mat = 2;               n0 = blockIdx.y * NTILE; }
    const bf16_t* W  = (MODE == 2) ? nullptr
                                   : (Wb + (size_t)((MODE == 0) ? mat : 2) * 262144);
    const float*  Bi = (MODE == 0) ? (mat == 0 ? B0 : B1) : B0;

    const int wr = (w >> 1) * 64;
    const int wc = (w & 1) * (NTILE / 2);
    const int srow = tid >> 3, scol = (tid & 7) * 8;

    f32x4 acc[4][NTN];
#pragma unroll
    for (int a = 0; a < 4; ++a)
#pragma unroll
        for (int b = 0; b < NTN; ++b) acc[a][b] = f32x4{0.f, 0.f, 0.f, 0.f};

    bf16x8 xp[4];
    bf16x8 wpb[NTN];
    f32x8  wpf[NTN];

#pragma unroll
    for (int it = 0; it < 4; ++it)
        xp[it] = *(const bf16x8*)(Xb + (size_t)(m0 + it * 32 + srow) * EMBED + scol);
#pragma unroll
    for (int it = 0; it < NTN; ++it) {
        const int r = it * 32 + srow;
        if (MODE != 2) wpb[it] = *(const bf16x8*)(W + (size_t)(n0 + r) * EMBED + scol);
        else           wpf[it] = *(const f32x8*)(Wf + (size_t)(n0 + r) * EMBED + scol);
    }

#pragma unroll 1
    for (int kt = 0; kt < 8; ++kt) {
        __syncthreads();
#pragma unroll
        for (int it = 0; it < 4; ++it)
            *(bf16x8*)(As + (it * 32 + srow) * 72 + scol) = xp[it];
#pragma unroll
        for (int it = 0; it < NTN; ++it) {
            const int r = it * 32 + srow;
            if (MODE != 2) *(bf16x8*)(Bs + r * 72 + scol) = wpb[it];
            else *(bf16x8*)(Bs + r * 72 + scol) = __builtin_convertvector(wpf[it], bf16x8);
        }
        if (kt < 7) {
            const int k1 = (kt + 1) * 64;
#pragma unroll
            for (int it = 0; it < 4; ++it)
                xp[it] = *(const bf16x8*)(Xb + (size_t)(m0 + it * 32 + srow) * EMBED + k1 + scol);
#pragma unroll
            for (int it = 0; it < NTN; ++it) {
                const int r = it * 32 + srow;
                if (MODE != 2) wpb[it] = *(const bf16x8*)(W + (size_t)(n0 + r) * EMBED + k1 + scol);
                else           wpf[it] = *(const f32x8*)(Wf + (size_t)(n0 + r) * EMBED + k1 + scol);
            }
        }
        __syncthreads();
#pragma unroll
        for (int ks = 0; ks < 2; ++ks) {
            const int ko = (ks * 4 + quad) * 8;
            bf16x8 av[4], bv[NTN];
#pragma unroll
            for (int mt = 0; mt < 4; ++mt)
                av[mt] = *(const bf16x8*)(As + (wr + mt * 16 + l15) * 72 + ko);
#pragma unroll
            for (int nt = 0; nt < NTN; ++nt)
                bv[nt] = *(const bf16x8*)(Bs + (wc + nt * 16 + l15) * 72 + ko);
            if (MODE == 0) {
#pragma unroll
                for (int a = 0; a < NTN; ++a)
#pragma unroll
                    for (int b = 0; b < 4; ++b)
                        acc[a][b] = mfma16(bv[a], av[b], acc[a][b]);   // n=row-run, m=col
            } else {
#pragma unroll
                for (int a = 0; a < 4; ++a)
#pragma unroll
                    for (int b = 0; b < NTN; ++b)
                        acc[a][b] = mfma16(av[a], bv[b], acc[a][b]);   // m=row-run, n=col
            }
        }
    }

    if (MODE == 0) {
        // acc[at][bt]: n = wc+at*16+quad*4+i, m = wr+bt*16+l15 -> T[m][n]
        bf16_t* T = SMEM;
        __syncthreads();
        const float scl = (mat == 0) ? SCQ : 1.0f;
#pragma unroll
        for (int at = 0; at < 4; ++at) {
            const int nb = wc + at * 16 + quad * 4;
            const f32x4 b4 = *(const f32x4*)(Bi + n0 + nb);
#pragma unroll
            for (int bt = 0; bt < 4; ++bt) {
                const int m = wr + bt * 16 + l15;
                bf16x4 pk;
#pragma unroll
                for (int i = 0; i < 4; ++i)
                    pk[i] = (bf16_t)(gelu_f(acc[at][bt][i] + b4[i]) * scl);
                *(bf16x4*)(T + m * 136 + nb) = pk;
            }
        }
        __syncthreads();
        // 32 chunks of 1 KB lane-contiguous: chunk -> (head-half, s-group)
        bf16_t* O = (mat == 0) ? O0 : O1;
#pragma unroll
        for (int it = 0; it < 8; ++it) {
            const int chunk = w * 8 + it;
            const int hh = chunk >> 4, sg = chunk & 15;
            const int sr = lane >> 3, dc = (lane & 7) * 8;
            const int m = m0 + sg * 8 + sr;
            const int bb = m >> 11, s = m & (SEQ - 1);
            const int h = (n0 + hh * 64) >> 6;
            const bf16x8 v = *(const bf16x8*)(T + (sg * 8 + sr) * 136 + hh * 64 + dc);
            *(bf16x8*)(O + (((size_t)(bb * NH + h)) * SEQ + s) * HD + dc) = v;
        }
    } else if (MODE == 1) {
        // acc[mt][nt]: m = wr+mt*16+quad*4+i, n = wc+nt*16+l15 -> T[n][m]
        bf16_t* T = SMEM;
        __syncthreads();
#pragma unroll
        for (int mt = 0; mt < 4; ++mt) {
            const int mloc = wr + mt * 16 + quad * 4;
#pragma unroll
            for (int nt = 0; nt < 4; ++nt) {
                const int nloc = wc + nt * 16 + l15;
                const float bs = Bi[n0 + nloc];
                bf16x4 pk;
#pragma unroll
                for (int i = 0; i < 4; ++i)
                    pk[i] = (bf16_t)gelu_f(acc[mt][nt][i] + bs);
                *(bf16x4*)(T + nloc * 136 + mloc) = pk;
            }
        }
        __syncthreads();
        // 32 chunks of 4 x 256-B contiguous (h,d)-row s-segments
        const int bb = m0 >> 11, sbase = m0 & (SEQ - 1);
#pragma unroll
        for (int it = 0; it < 8; ++it) {
            const int chunk = w * 8 + it;
            const int r = lane >> 4, sc = (lane & 15) * 8;
            const int nloc = chunk * 4 + r;
            const int fc = n0 + nloc, h = fc >> 6, d = fc & 63;
            const bf16x8 v = *(const bf16x8*)(T + nloc * 136 + sc);
            *(bf16x8*)(O2 + ((size_t)(bb * NH + h) * HD + d) * SEQ + sbase + sc) = v;
        }
    } else {
        // fp32 natural store, coalesced
#pragma unroll
        for (int mt = 0; mt < 4; ++mt) {
            const int mb = m0 + wr + mt * 16 + quad * 4;
#pragma unroll
            for (int nt = 0; nt < NTN; ++nt) {
                const int fc = n0 + wc + nt * 16 + l15;
                const float bs = Bi[fc];
#pragma unroll
                for (int i = 0; i < 4; ++i)
                    Of[(size_t)(mb + i) * EMBED + fc] = gelu_f(acc[mt][nt][i] + bs);
            }
        }
    }
}

// ---------------------------------------------------------------------------
// Flash attention, q-tile 128 (was 64): halves per-byte K/V refetch.
// Q pre-scaled by log2(e)/8 => p = exp2(s-8) (exact; shift cancels in O/l).
// S^T = K*Q^T gives P[q=l15][key=quad*4+i]; P round-trips per-wave LDS
// (no barrier); PV reads P back as A-fragments.
// 4 waves x 32 q-rows; KV tile 64 double-buffered; grid 16x32.
// LDS 55.3 KB -> 2 blocks/CU.
// ---------------------------------------------------------------------------
__global__ __launch_bounds__(256, 2)
void flash_attn_kernel(const bf16_t* __restrict__ Q,
                       const bf16_t* __restrict__ K,
                       const bf16_t* __restrict__ Vt,
                       bf16_t* __restrict__ Og)
{
    __shared__ __align__(16) bf16_t Ks[2][64 * 72];
    __shared__ __align__(16) bf16_t Vs[2][64 * 72];
    __shared__ __align__(16) bf16_t Ps[4][32 * 72];

    const int tid  = threadIdx.x;
    const int lane = tid & 63, w = tid >> 6, quad = lane >> 4, l15 = lane & 15;
    const int bh = blockIdx.y;
    const int q0 = blockIdx.x * 128;
    const size_t baseQK = (size_t)bh * SEQ * HD;
    const size_t baseV  = (size_t)bh * HD * SEQ;
    const int wm = w * 32;

    bf16x8 qf[2][2];
#pragma unroll
    for (int mt = 0; mt < 2; ++mt)
#pragma unroll
        for (int ks = 0; ks < 2; ++ks)
            qf[mt][ks] = *(const bf16x8*)(Q + baseQK +
                (size_t)(q0 + wm + mt * 16 + l15) * HD + ks * 32 + quad * 8);

    float lsum[2] = {0.f, 0.f};
    f32x4 oacc[2][4];
#pragma unroll
    for (int mt = 0; mt < 2; ++mt)
#pragma unroll
        for (int nt = 0; nt < 4; ++nt) oacc[mt][nt] = f32x4{0.f, 0.f, 0.f, 0.f};

    bf16_t* Pw = Ps[w];
    const int r0 = tid >> 3, c0 = (tid & 7) * 8;
    bf16x8 kr0, kr1, vr0, vr1;

    kr0 = *(const bf16x8*)(K + baseQK + (size_t)r0 * HD + c0);
    kr1 = *(const bf16x8*)(K + baseQK + (size_t)(r0 + 32) * HD + c0);
    vr0 = *(const bf16x8*)(Vt + baseV + (size_t)r0 * SEQ + c0);
    vr1 = *(const bf16x8*)(Vt + baseV + (size_t)(r0 + 32) * SEQ + c0);
    *(bf16x8*)(Ks[0] + r0 * 72 + c0)        = kr0;
    *(bf16x8*)(Ks[0] + (r0 + 32) * 72 + c0) = kr1;
    *(bf16x8*)(Vs[0] + r0 * 72 + c0)        = vr0;
    *(bf16x8*)(Vs[0] + (r0 + 32) * 72 + c0) = vr1;
    kr0 = *(const bf16x8*)(K + baseQK + (size_t)(64 + r0) * HD + c0);
    kr1 = *(const bf16x8*)(K + baseQK + (size_t)(64 + r0 + 32) * HD + c0);
    vr0 = *(const bf16x8*)(Vt + baseV + (size_t)r0 * SEQ + 64 + c0);
    vr1 = *(const bf16x8*)(Vt + baseV + (size_t)(r0 + 32) * SEQ + 64 + c0);

#pragma unroll 1
    for (int t = 0; t < 32; ++t) {
        __syncthreads();
        if (t + 1 < 32) {
            bf16_t* Kn = Ks[(t + 1) & 1];
            bf16_t* Vn = Vs[(t + 1) & 1];
            *(bf16x8*)(Kn + r0 * 72 + c0)        = kr0;
            *(bf16x8*)(Kn + (r0 + 32) * 72 + c0) = kr1;
            *(bf16x8*)(Vn + r0 * 72 + c0)        = vr0;
            *(bf16x8*)(Vn + (r0 + 32) * 72 + c0) = vr1;
        }
        if (t + 2 < 32) {
            const int kv = (t + 2) * 64;
            kr0 = *(const bf16x8*)(K + baseQK + (size_t)(kv + r0) * HD + c0);
            kr1 = *(const bf16x8*)(K + baseQK + (size_t)(kv + r0 + 32) * HD + c0);
            vr0 = *(const bf16x8*)(Vt + baseV + (size_t)r0 * SEQ + kv + c0);
            vr1 = *(const bf16x8*)(Vt + baseV + (size_t)(r0 + 32) * SEQ + kv + c0);
        }

        const bf16_t* Kb = Ks[t & 1];
        const bf16_t* Vb = Vs[t & 1];

        // S^T = K Q^T : lane holds S[q = mt*16+l15][key = jt*16 + quad*4 + i]
        f32x4 sf[2][4];
#pragma unroll
        for (int mt = 0; mt < 2; ++mt)
#pragma unroll
            for (int jt = 0; jt < 4; ++jt) sf[mt][jt] = f32x4{0.f, 0.f, 0.f, 0.f};
#pragma unroll
        for (int ks = 0; ks < 2; ++ks) {
            const int ko = ks * 32 + quad * 8;
#pragma unroll
            for (int jt = 0; jt < 4; ++jt) {
                const bf16x8 a = *(const bf16x8*)(Kb + (jt * 16 + l15) * 72 + ko);
                sf[0][jt] = mfma16(a, qf[0][ks], sf[0][jt]);
                sf[1][jt] = mfma16(a, qf[1][ks], sf[1][jt]);
            }
        }

#pragma unroll
        for (int mt = 0; mt < 2; ++mt)
#pragma unroll
            for (int jt = 0; jt < 4; ++jt) {
                f32x4 p;
#pragma unroll
                for (int i = 0; i < 4; ++i) {
                    p[i] = exp2f(sf[mt][jt][i] - 8.f);
                    lsum[mt] += p[i];
                }
                const bf16x4 pk = __builtin_convertvector(p, bf16x4);
                *(bf16x4*)(Pw + (mt * 16 + l15) * 72 + jt * 16 + quad * 4) = pk;
            }

#pragma unroll
        for (int c = 0; c < 2; ++c) {
            const int ko = c * 32 + quad * 8;
            const bf16x8 a0 = *(const bf16x8*)(Pw + l15 * 72 + ko);
            const bf16x8 a1 = *(const bf16x8*)(Pw + (16 + l15) * 72 + ko);
#pragma unroll
            for (int nt = 0; nt < 4; ++nt) {
                const bf16x8 b = *(const bf16x8*)(Vb + (nt * 16 + l15) * 72 + ko);
                oacc[0][nt] = mfma16(a0, b, oacc[0][nt]);
                oacc[1][nt] = mfma16(a1, b, oacc[1][nt]);
            }
        }
    }

    const int bidx = bh >> 3, h = bh & 7;
#pragma unroll
    for (int mt = 0; mt < 2; ++mt) {
        float rs = lsum[mt];
        rs += __shfl_xor(rs, 16);
        rs += __shfl_xor(rs, 32);
        float lf[4];
#pragma unroll
        for (int i = 0; i < 4; ++i)
            lf[i] = __shfl(rs, (lane & 48) | (quad * 4 + i));
#pragma unroll
        for (int nt = 0; nt < 4; ++nt)
#pragma unroll
            for (int i = 0; i < 4; ++i) {
                const int s = q0 + wm + mt * 16 + quad * 4 + i;
                const int d = nt * 16 + l15;
                Og[((size_t)(bidx * SEQ + s)) * EMBED + h * HD + d] =
                    (bf16_t)(oacc[mt][nt][i] / lf[i]);
            }
    }
}

extern "C" void kernel_launch(void* const* d_in, const int* in_sizes, int n_in,
                              void* d_out, int out_size, void* d_ws, size_t ws_size,
                              hipStream_t stream)
{
    const float* x  = (const float*)d_in[0];
    const float* Wq = (const float*)d_in[1];
    const float* bq = (const float*)d_in[2];
    const float* Wk = (const float*)d_in[3];
    const float* bk = (const float*)d_in[4];
    const float* Wv = (const float*)d_in[5];
    const float* bv = (const float*)d_in[6];
    const float* Wo = (const float*)d_in[7];
    const float* bo = (const float*)d_in[8];
    float* out = (float*)d_out;

    const size_t NE = (size_t)MTOT * EMBED;
    bf16_t* xb  = (bf16_t*)d_out;          // dead after QKV GEMMs
    bf16_t* Qw  = (bf16_t*)d_out + NE;     // dead after flash
    bf16_t* Kw  = (bf16_t*)d_ws;
    bf16_t* Vtw = Kw + NE;
    bf16_t* Ow  = Vtw + NE;
    bf16_t* Wb  = Ow;                      // weights dead before flash writes Ow

    convert_kernel<<<dim3(64, 19), 256, 0, stream>>>(x, Wq, Wk, Wv, xb, Wb);
    gemm_gelu_kernel<0, 128><<<dim3(64, 8), 256, 0, stream>>>(
        xb, Wb, nullptr, bq, bk, Qw, Kw, nullptr, nullptr);     // Q, K (swapped)
    gemm_gelu_kernel<1, 128><<<dim3(64, 4), 256, 0, stream>>>(
        xb, Wb, nullptr, bv, nullptr, nullptr, nullptr, Vtw, nullptr);  // V
    flash_attn_kernel<<<dim3(16, 32), 256, 0, stream>>>(Qw, Kw, Vtw, Ow);
    gemm_gelu_kernel<2, 64><<<dim3(64, 8), 256, 0, stream>>>(
        Ow, nullptr, Wo, bo, nullptr, nullptr, nullptr, nullptr, out);  // out-proj
}

// Round 11
// 197.496 us; speedup vs baseline: 1.4604x; 1.0090x over previous
//
#include <hip/hip_runtime.h>
#include <hip/hip_bf16.h>

typedef __bf16 bf16_t;
typedef __bf16 bf16x4 __attribute__((ext_vector_type(4)));
typedef __bf16 bf16x8 __attribute__((ext_vector_type(8)));
typedef float  f32x4  __attribute__((ext_vector_type(4)));
typedef float  f32x8  __attribute__((ext_vector_type(8)));

#define EMBED 512
#define NH    8
#define HD    64
#define SEQ   2048
#define MTOT  8192
#define SCQ   0.18033688011112042f   // log2(e) / sqrt(64), folded into Q

__device__ __forceinline__ float gelu_f(float x) {
    return 0.5f * x * (1.0f + erff(x * 0.7071067811865475f));
}

__device__ __forceinline__ f32x4 mfma16(bf16x8 a, bf16x8 b, f32x4 c) {
    return __builtin_amdgcn_mfma_f32_16x16x32_bf16(a, b, c, 0, 0, 0);
}

// ---------------------------------------------------------------------------
// Pre-convert fp32 -> bf16: x (16 segments of 256K elems) + Wq/Wk/Wv.
// ---------------------------------------------------------------------------
__global__ __launch_bounds__(256)
void convert_kernel(const float* __restrict__ x,  const float* __restrict__ Wq,
                    const float* __restrict__ Wk, const float* __restrict__ Wv,
                    bf16_t* __restrict__ xb, bf16_t* __restrict__ wb)
{
    const int y = blockIdx.y;
    const float* src; bf16_t* dst;
    if (y < 16)      { src = x + (size_t)y * 262144; dst = xb + (size_t)y * 262144; }
    else if (y == 16){ src = Wq; dst = wb; }
    else if (y == 17){ src = Wk; dst = wb + 262144; }
    else             { src = Wv; dst = wb + 524288; }
    const int base = (blockIdx.x * 256 + threadIdx.x) * 16;
    const f32x8 a = *(const f32x8*)(src + base);
    const f32x8 b = *(const f32x8*)(src + base + 8);
    *(bf16x8*)(dst + base)     = __builtin_convertvector(a, bf16x8);
    *(bf16x8*)(dst + base + 8) = __builtin_convertvector(b, bf16x8);
}

// ---------------------------------------------------------------------------
// GEMM + bias + GELU.
// MODE 0: merged QKV (grid 64x12, mat=y>>2): ONE static operand-swapped
//   MFMA loop (acc reg-run along n) — R7-R9 spill was two orientations
//   behind a runtime branch in the K-loop; epilogue-only branching is safe
//   (acc read-only there). Q/K: T[m][n] -> 1 KB lane-contiguous bursts.
//   V: T[n][m] via scalar writes (32B runs, 2-way = free) -> 256 B bursts.
// MODE 2: out-proj, W fp32, natural MFMA, coalesced fp32 store.
// 128 x NTILE tile, BK=64, 4 waves, register prefetch of next k-tile.
// ---------------------------------------------------------------------------
template<int MODE, int NTILE>
__global__ __launch_bounds__(256, 3)
void gemm_gelu_kernel(const bf16_t* __restrict__ Xb,
                      const bf16_t* __restrict__ Wb,   // MODE 0
                      const float*  __restrict__ Wf,   // MODE 2
                      const float*  __restrict__ B0,   // bq  / bo
                      const float*  __restrict__ B1,   // bk
                      const float*  __restrict__ B2,   // bv
                      bf16_t* __restrict__ O0, bf16_t* __restrict__ O1,
                      bf16_t* __restrict__ O2, float* __restrict__ Of)
{
    constexpr int NTN = NTILE / 32;
    __shared__ __align__(16) bf16_t SMEM[128 * 72 + NTILE * 72];
    bf16_t* As = SMEM;
    bf16_t* Bs = SMEM + 128 * 72;
    const int tid  = threadIdx.x;
    const int lane = tid & 63, w = tid >> 6, quad = lane >> 4, l15 = lane & 15;
    const int m0 = blockIdx.x * 128;
    int mat, n0;
    if (MODE == 0) { mat = blockIdx.y >> 2; n0 = (blockIdx.y & 3) * 128; }
    else           { mat = 0;               n0 = blockIdx.y * NTILE; }
    const bf16_t* W  = (MODE == 0) ? (Wb + (size_t)mat * 262144) : nullptr;
    const float*  Bi = (MODE == 0) ? (mat == 0 ? B0 : (mat == 1 ? B1 : B2)) : B0;

    const int wr = (w >> 1) * 64;
    const int wc = (w & 1) * (NTILE / 2);
    const int srow = tid >> 3, scol = (tid & 7) * 8;

    f32x4 acc[4][NTN];
#pragma unroll
    for (int a = 0; a < 4; ++a)
#pragma unroll
        for (int b = 0; b < NTN; ++b) acc[a][b] = f32x4{0.f, 0.f, 0.f, 0.f};

    bf16x8 xp[4];
    bf16x8 wpb[NTN];
    f32x8  wpf[NTN];

#pragma unroll
    for (int it = 0; it < 4; ++it)
        xp[it] = *(const bf16x8*)(Xb + (size_t)(m0 + it * 32 + srow) * EMBED + scol);
#pragma unroll
    for (int it = 0; it < NTN; ++it) {
        const int r = it * 32 + srow;
        if (MODE == 0) wpb[it] = *(const bf16x8*)(W + (size_t)(n0 + r) * EMBED + scol);
        else           wpf[it] = *(const f32x8*)(Wf + (size_t)(n0 + r) * EMBED + scol);
    }

#pragma unroll 1
    for (int kt = 0; kt < 8; ++kt) {
        __syncthreads();
#pragma unroll
        for (int it = 0; it < 4; ++it)
            *(bf16x8*)(As + (it * 32 + srow) * 72 + scol) = xp[it];
#pragma unroll
        for (int it = 0; it < NTN; ++it) {
            const int r = it * 32 + srow;
            if (MODE == 0) *(bf16x8*)(Bs + r * 72 + scol) = wpb[it];
            else *(bf16x8*)(Bs + r * 72 + scol) = __builtin_convertvector(wpf[it], bf16x8);
        }
        if (kt < 7) {
            const int k1 = (kt + 1) * 64;
#pragma unroll
            for (int it = 0; it < 4; ++it)
                xp[it] = *(const bf16x8*)(Xb + (size_t)(m0 + it * 32 + srow) * EMBED + k1 + scol);
#pragma unroll
            for (int it = 0; it < NTN; ++it) {
                const int r = it * 32 + srow;
                if (MODE == 0) wpb[it] = *(const bf16x8*)(W + (size_t)(n0 + r) * EMBED + k1 + scol);
                else           wpf[it] = *(const f32x8*)(Wf + (size_t)(n0 + r) * EMBED + k1 + scol);
            }
        }
        __syncthreads();
#pragma unroll
        for (int ks = 0; ks < 2; ++ks) {
            const int ko = (ks * 4 + quad) * 8;
            bf16x8 av[4], bv[NTN];
#pragma unroll
            for (int mt = 0; mt < 4; ++mt)
                av[mt] = *(const bf16x8*)(As + (wr + mt * 16 + l15) * 72 + ko);
#pragma unroll
            for (int nt = 0; nt < NTN; ++nt)
                bv[nt] = *(const bf16x8*)(Bs + (wc + nt * 16 + l15) * 72 + ko);
            if (MODE == 0) {
#pragma unroll
                for (int a = 0; a < NTN; ++a)
#pragma unroll
                    for (int b = 0; b < 4; ++b)
                        acc[a][b] = mfma16(bv[a], av[b], acc[a][b]);   // n=row-run, m=col
            } else {
#pragma unroll
                for (int a = 0; a < 4; ++a)
#pragma unroll
                    for (int b = 0; b < NTN; ++b)
                        acc[a][b] = mfma16(av[a], bv[b], acc[a][b]);   // m=row-run, n=col
            }
        }
    }

    if (MODE == 0) {
        // swapped acc[at][bt]: n = wc+at*16+quad*4+i, m = wr+bt*16+l15
        bf16_t* T = SMEM;
        __syncthreads();
        if (mat < 2) {
            const float scl = (mat == 0) ? SCQ : 1.0f;
#pragma unroll
            for (int at = 0; at < 4; ++at) {
                const int nb = wc + at * 16 + quad * 4;
                const f32x4 b4 = *(const f32x4*)(Bi + n0 + nb);
#pragma unroll
                for (int bt = 0; bt < 4; ++bt) {
                    const int m = wr + bt * 16 + l15;
                    bf16x4 pk;
#pragma unroll
                    for (int i = 0; i < 4; ++i)
                        pk[i] = (bf16_t)(gelu_f(acc[at][bt][i] + b4[i]) * scl);
                    *(bf16x4*)(T + m * 136 + nb) = pk;   // T[m][n]
                }
            }
        } else {
#pragma unroll
            for (int at = 0; at < 4; ++at) {
                const int nb = wc + at * 16 + quad * 4;
                const f32x4 b4 = *(const f32x4*)(Bi + n0 + nb);
#pragma unroll
                for (int bt = 0; bt < 4; ++bt) {
                    const int m = wr + bt * 16 + l15;
#pragma unroll
                    for (int i = 0; i < 4; ++i)   // scalar: 32B runs, 2-way = free
                        T[(nb + i) * 136 + m] = (bf16_t)gelu_f(acc[at][bt][i] + b4[i]);
                }
            }
        }
        __syncthreads();
        if (mat < 2) {
            // 32 chunks of 1 KB lane-contiguous: chunk -> (head-half, s-group)
            bf16_t* O = (mat == 0) ? O0 : O1;
#pragma unroll
            for (int it = 0; it < 8; ++it) {
                const int chunk = w * 8 + it;
                const int hh = chunk >> 4, sg = chunk & 15;
                const int sr = lane >> 3, dc = (lane & 7) * 8;
                const int m = m0 + sg * 8 + sr;
                const int bb = m >> 11, s = m & (SEQ - 1);
                const int h = (n0 + hh * 64) >> 6;
                const bf16x8 v = *(const bf16x8*)(T + (sg * 8 + sr) * 136 + hh * 64 + dc);
                *(bf16x8*)(O + (((size_t)(bb * NH + h)) * SEQ + s) * HD + dc) = v;
            }
        } else {
            // 32 chunks of 4 x 256-B contiguous (h,d)-row s-segments
            const int bb = m0 >> 11, sbase = m0 & (SEQ - 1);
#pragma unroll
            for (int it = 0; it < 8; ++it) {
                const int chunk = w * 8 + it;
                const int r = lane >> 4, sc = (lane & 15) * 8;
                const int nloc = chunk * 4 + r;
                const int fc = n0 + nloc, h = fc >> 6, d = fc & 63;
                const bf16x8 v = *(const bf16x8*)(T + nloc * 136 + sc);
                *(bf16x8*)(O2 + ((size_t)(bb * NH + h) * HD + d) * SEQ + sbase + sc) = v;
            }
        }
    } else {
        // fp32 natural store, coalesced
#pragma unroll
        for (int mt = 0; mt < 4; ++mt) {
            const int mb = m0 + wr + mt * 16 + quad * 4;
#pragma unroll
            for (int nt = 0; nt < NTN; ++nt) {
                const int fc = n0 + wc + nt * 16 + l15;
                const float bs = Bi[fc];
#pragma unroll
                for (int i = 0; i < 4; ++i)
                    Of[(size_t)(mb + i) * EMBED + fc] = gelu_f(acc[mt][nt][i] + bs);
            }
        }
    }
}

// ---------------------------------------------------------------------------
// Flash attention, q-tile 128, KV tile 64 double-buffered, grid 16x32.
// K/V LDS UNPADDED (stride 64) -> LDS 51.2 KB -> 3 blocks/CU (was 2).
// Q pre-scaled by log2(e)/8 => p = exp2(s-8) (exact; shift cancels in O/l).
// S^T = K*Q^T gives P[q=l15][key=quad*4+i]; P round-trips per-wave LDS
// (stride 72, no barrier); PV reads P back as A-fragments.
// ---------------------------------------------------------------------------
__global__ __launch_bounds__(256, 3)
void flash_attn_kernel(const bf16_t* __restrict__ Q,
                       const bf16_t* __restrict__ K,
                       const bf16_t* __restrict__ Vt,
                       bf16_t* __restrict__ Og)
{
    __shared__ __align__(16) bf16_t Ks[2][64 * 64];
    __shared__ __align__(16) bf16_t Vs[2][64 * 64];
    __shared__ __align__(16) bf16_t Ps[4][32 * 72];

    const int tid  = threadIdx.x;
    const int lane = tid & 63, w = tid >> 6, quad = lane >> 4, l15 = lane & 15;
    const int bh = blockIdx.y;
    const int q0 = blockIdx.x * 128;
    const size_t baseQK = (size_t)bh * SEQ * HD;
    const size_t baseV  = (size_t)bh * HD * SEQ;
    const int wm = w * 32;

    bf16x8 qf[2][2];
#pragma unroll
    for (int mt = 0; mt < 2; ++mt)
#pragma unroll
        for (int ks = 0; ks < 2; ++ks)
            qf[mt][ks] = *(const bf16x8*)(Q + baseQK +
                (size_t)(q0 + wm + mt * 16 + l15) * HD + ks * 32 + quad * 8);

    float lsum[2] = {0.f, 0.f};
    f32x4 oacc[2][4];
#pragma unroll
    for (int mt = 0; mt < 2; ++mt)
#pragma unroll
        for (int nt = 0; nt < 4; ++nt) oacc[mt][nt] = f32x4{0.f, 0.f, 0.f, 0.f};

    bf16_t* Pw = Ps[w];
    const int r0 = tid >> 3, c0 = (tid & 7) * 8;
    bf16x8 kr0, kr1, vr0, vr1;

    kr0 = *(const bf16x8*)(K + baseQK + (size_t)r0 * HD + c0);
    kr1 = *(const bf16x8*)(K + baseQK + (size_t)(r0 + 32) * HD + c0);
    vr0 = *(const bf16x8*)(Vt + baseV + (size_t)r0 * SEQ + c0);
    vr1 = *(const bf16x8*)(Vt + baseV + (size_t)(r0 + 32) * SEQ + c0);
    *(bf16x8*)(Ks[0] + r0 * 64 + c0)        = kr0;
    *(bf16x8*)(Ks[0] + (r0 + 32) * 64 + c0) = kr1;
    *(bf16x8*)(Vs[0] + r0 * 64 + c0)        = vr0;
    *(bf16x8*)(Vs[0] + (r0 + 32) * 64 + c0) = vr1;
    kr0 = *(const bf16x8*)(K + baseQK + (size_t)(64 + r0) * HD + c0);
    kr1 = *(const bf16x8*)(K + baseQK + (size_t)(64 + r0 + 32) * HD + c0);
    vr0 = *(const bf16x8*)(Vt + baseV + (size_t)r0 * SEQ + 64 + c0);
    vr1 = *(const bf16x8*)(Vt + baseV + (size_t)(r0 + 32) * SEQ + 64 + c0);

#pragma unroll 1
    for (int t = 0; t < 32; ++t) {
        __syncthreads();
        if (t + 1 < 32) {
            bf16_t* Kn = Ks[(t + 1) & 1];
            bf16_t* Vn = Vs[(t + 1) & 1];
            *(bf16x8*)(Kn + r0 * 64 + c0)        = kr0;
            *(bf16x8*)(Kn + (r0 + 32) * 64 + c0) = kr1;
            *(bf16x8*)(Vn + r0 * 64 + c0)        = vr0;
            *(bf16x8*)(Vn + (r0 + 32) * 64 + c0) = vr1;
        }
        if (t + 2 < 32) {
            const int kv = (t + 2) * 64;
            kr0 = *(const bf16x8*)(K + baseQK + (size_t)(kv + r0) * HD + c0);
            kr1 = *(const bf16x8*)(K + baseQK + (size_t)(kv + r0 + 32) * HD + c0);
            vr0 = *(const bf16x8*)(Vt + baseV + (size_t)r0 * SEQ + kv + c0);
            vr1 = *(const bf16x8*)(Vt + baseV + (size_t)(r0 + 32) * SEQ + kv + c0);
        }

        const bf16_t* Kb = Ks[t & 1];
        const bf16_t* Vb = Vs[t & 1];

        // S^T = K Q^T : lane holds S[q = mt*16+l15][key = jt*16 + quad*4 + i]
        f32x4 sf[2][4];
#pragma unroll
        for (int mt = 0; mt < 2; ++mt)
#pragma unroll
            for (int jt = 0; jt < 4; ++jt) sf[mt][jt] = f32x4{0.f, 0.f, 0.f, 0.f};
#pragma unroll
        for (int ks = 0; ks < 2; ++ks) {
            const int ko = ks * 32 + quad * 8;
#pragma unroll
            for (int jt = 0; jt < 4; ++jt) {
                const bf16x8 a = *(const bf16x8*)(Kb + (jt * 16 + l15) * 64 + ko);
                sf[0][jt] = mfma16(a, qf[0][ks], sf[0][jt]);
                sf[1][jt] = mfma16(a, qf[1][ks], sf[1][jt]);
            }
        }

#pragma unroll
        for (int mt = 0; mt < 2; ++mt)
#pragma unroll
            for (int jt = 0; jt < 4; ++jt) {
                f32x4 p;
#pragma unroll
                for (int i = 0; i < 4; ++i) {
                    p[i] = exp2f(sf[mt][jt][i] - 8.f);
                    lsum[mt] += p[i];
                }
                const bf16x4 pk = __builtin_convertvector(p, bf16x4);
                *(bf16x4*)(Pw + (mt * 16 + l15) * 72 + jt * 16 + quad * 4) = pk;
            }

#pragma unroll
        for (int c = 0; c < 2; ++c) {
            const int ko = c * 32 + quad * 8;
            const bf16x8 a0 = *(const bf16x8*)(Pw + l15 * 72 + ko);
            const bf16x8 a1 = *(const bf16x8*)(Pw + (16 + l15) * 72 + ko);
#pragma unroll
            for (int nt = 0; nt < 4; ++nt) {
                const bf16x8 b = *(const bf16x8*)(Vb + (nt * 16 + l15) * 64 + ko);
                oacc[0][nt] = mfma16(a0, b, oacc[0][nt]);
                oacc[1][nt] = mfma16(a1, b, oacc[1][nt]);
            }
        }
    }

    const int bidx = bh >> 3, h = bh & 7;
#pragma unroll
    for (int mt = 0; mt < 2; ++mt) {
        float rs = lsum[mt];
        rs += __shfl_xor(rs, 16);
        rs += __shfl_xor(rs, 32);
        float lf[4];
#pragma unroll
        for (int i = 0; i < 4; ++i)
            lf[i] = __shfl(rs, (lane & 48) | (quad * 4 + i));
#pragma unroll
        for (int nt = 0; nt < 4; ++nt)
#pragma unroll
            for (int i = 0; i < 4; ++i) {
                const int s = q0 + wm + mt * 16 + quad * 4 + i;
                const int d = nt * 16 + l15;
                Og[((size_t)(bidx * SEQ + s)) * EMBED + h * HD + d] =
                    (bf16_t)(oacc[mt][nt][i] / lf[i]);
            }
    }
}

extern "C" void kernel_launch(void* const* d_in, const int* in_sizes, int n_in,
                              void* d_out, int out_size, void* d_ws, size_t ws_size,
                              hipStream_t stream)
{
    const float* x  = (const float*)d_in[0];
    const float* Wq = (const float*)d_in[1];
    const float* bq = (const float*)d_in[2];
    const float* Wk = (const float*)d_in[3];
    const float* bk = (const float*)d_in[4];
    const float* Wv = (const float*)d_in[5];
    const float* bv = (const float*)d_in[6];
    const float* Wo = (const float*)d_in[7];
    const float* bo = (const float*)d_in[8];
    float* out = (float*)d_out;

    const size_t NE = (size_t)MTOT * EMBED;
    bf16_t* xb  = (bf16_t*)d_out;          // dead after QKV GEMM
    bf16_t* Qw  = (bf16_t*)d_out + NE;     // dead after flash
    bf16_t* Kw  = (bf16_t*)d_ws;
    bf16_t* Vtw = Kw + NE;
    bf16_t* Ow  = Vtw + NE;
    bf16_t* Wb  = Ow;                      // weights dead before flash writes Ow

    convert_kernel<<<dim3(64, 19), 256, 0, stream>>>(x, Wq, Wk, Wv, xb, Wb);
    gemm_gelu_kernel<0, 128><<<dim3(64, 12), 256, 0, stream>>>(
        xb, Wb, nullptr, bq, bk, bv, Qw, Kw, Vtw, nullptr);     // merged QKV
    flash_attn_kernel<<<dim3(16, 32), 256, 0, stream>>>(Qw, Kw, Vtw, Ow);
    gemm_gelu_kernel<2, 64><<<dim3(64, 8), 256, 0, stream>>>(
        Ow, nullptr, Wo, bo, nullptr, nullptr, nullptr, nullptr, nullptr, out);
}